// Round 4
// baseline (15380.182 us; speedup 1.0000x reference)
//
#include <hip/hip_runtime.h>
#include <hip/hip_bf16.h>
#include <stdint.h>

// Problem constants
#define BATCH   8192
#define IN_DIM  1024
#define N_HID   2048
#define OUT_DIM 256
#define SRC_DIM 3072

// Tiling
#define C     32                   // source columns per chunk
#define RB    16                   // rows per row-block (= rows per wave)
#define BT    256                  // batch per block (4/lane: 2l,2l+1,128+2l,128+2l+1)
#define S1_CH (IN_DIM / C)         // 32
#define S1_RB (N_HID / RB)         // 128
#define S2_CH (SRC_DIM / C)        // 96
#define S2_RB (OUT_DIM / RB)       // 16
#define NSEG1 (S1_RB * S1_CH)      // 4096
#define NSEG2 (S2_RB * S2_CH)      // 1536
#define ZSLOT 128                  // A-tile zero page (pad byte 0x80)
#define SEG_U32 160                // segment stride (640 B; max 15 overflow planes)
#define ABUF_U32 ((4 * C + 1) * 128)  // 16512 u32 = 64.5 KB per A-tile buffer

// Segment format v5 (granule-2 overflow; plane-0 identical to proven v3):
//   u32[0..7]   plane-0: row r -> u16 at byte 2r (2 slot bytes, pad 0x80)
//   overflow planes p=1..15 at u32 8+9(p-1), stride 9:
//     [0]    = 16-bit row mask (rows with n > 2p)
//     [1..8] = u16 per row: 2 slot bytes for overflow idx 2(p-1), 2(p-1)+1
//   hdr: W = total planes, wave-uniform.
// R1 LESSON: per-slot vector gating costs ~70 VALU/slot; plane-0 stays
// unconditional, pads hit the zero page.
// R2 LESSON: BT=256 halved per-element VALU; 1 block/CU exposes skew.
// R3 LESSON: dbuf + 1 barrier/chunk recovered most skew (206->157).
// R4: v_pk_add_f32 accumulate (ext_vector float2), granule-2 overflow
// (pad slots 30%->18%), straight-line planes 1-2 w/ speculative s_loads.

// ---------------------------------------------------------------------------
__global__ void k_prep(const int* __restrict__ mat,
                       uint32_t* __restrict__ seg1, uint32_t* __restrict__ seg2,
                       uint32_t* __restrict__ hdr1, uint32_t* __restrict__ hdr2) {
    int wid  = (blockIdx.x * blockDim.x + threadIdx.x) >> 6;
    int lane = threadIdx.x & 63;
    if (wid >= NSEG1 + NSEG2) return;

    int row0, col0;
    uint32_t *seg, *hdr;
    if (wid < NSEG1) {
        int rb = wid / S1_CH, ch = wid % S1_CH;
        row0 = rb * RB;          col0 = ch * C;
        seg = seg1 + (size_t)wid * SEG_U32;  hdr = hdr1 + wid;
    } else {
        int s  = wid - NSEG1;
        int rb = s / S2_CH, ch = s % S2_CH;
        row0 = N_HID + rb * RB;  col0 = ch * C;
        seg = seg2 + (size_t)s * SEG_U32;    hdr = hdr2 + s;
    }

    int n = 0;
    if (lane < RB) {
        const int* mrow = mat + (size_t)(row0 + lane) * SRC_DIM + col0;
        uint8_t* sb = (uint8_t*)seg;
        for (int c = 0; c < C; c++) {
            int code = mrow[c];
            if (code != 0) {
                uint8_t slot = (uint8_t)((code - 1) * C + c);
                if (n < 2) {
                    sb[2 * lane + n] = slot;               // plane-0 u16
                } else {
                    int j  = n - 2;                        // overflow index
                    int pl = j >> 1;                       // 0-based overflow plane
                    sb[(size_t)(8 + 9 * pl + 1 + (lane >> 1)) * 4
                       + (lane & 1) * 2 + (j & 1)] = slot;
                }
                n++;
            }
        }
    }
    int m = n;
    #pragma unroll
    for (int d = 1; d < 64; d <<= 1) m = max(m, __shfl_xor(m, d));
    uint32_t Wv = (m <= 2) ? 1u : 1u + (uint32_t)((m - 1) >> 1);

    for (uint32_t p = 1; p < Wv; p++) {
        unsigned long long b = __ballot(n > (int)(2 * p));
        if (lane == 0) seg[8 + 9 * (p - 1)] = (uint32_t)(b & 0xFFFFu);
    }
    if (lane == 0) *hdr = Wv;
}

// ---------------------------------------------------------------------------
// k_xt: transpose x[8192][1024] -> x_t[1024][8192] (fp32), 64x64 LDS tiles.
// ---------------------------------------------------------------------------
__global__ __launch_bounds__(256) void k_xt(const float* __restrict__ x,
                                            float* __restrict__ x_t) {
    __shared__ float t[64][65];
    const int b0 = blockIdx.x * 64, c0 = blockIdx.y * 64;
    {
        int r  = threadIdx.x >> 4;
        int cq = (threadIdx.x & 15) * 4;
        #pragma unroll
        for (int k = 0; k < 4; k++) {
            int rr = r + 16 * k;
            float4 v = *(const float4*)&x[(size_t)(b0 + rr) * IN_DIM + c0 + cq];
            t[rr][cq + 0] = v.x; t[rr][cq + 1] = v.y;
            t[rr][cq + 2] = v.z; t[rr][cq + 3] = v.w;
        }
    }
    __syncthreads();
    {
        int bq  = (threadIdx.x & 15) * 4;
        int cc0 = threadIdx.x >> 4;
        #pragma unroll
        for (int k = 0; k < 4; k++) {
            int cc = cc0 + 16 * k;
            float4 v;
            v.x = t[bq + 0][cc]; v.y = t[bq + 1][cc];
            v.z = t[bq + 2][cc]; v.w = t[bq + 3][cc];
            *(float4*)&x_t[(size_t)(c0 + cc) * BATCH + b0 + bq] = v;
        }
    }
}

typedef float v2f __attribute__((ext_vector_type(2)));

// pack two floats as bf16 pair: low16 = first, high16 = second
__device__ __forceinline__ uint32_t pack2(float a, float b) {
    __hip_bfloat162 h = __float22bfloat162_rn(make_float2(a, b));
    union { __hip_bfloat162 h2; uint32_t u; } u;
    u.h2 = h;
    return u.u;
}

__device__ __forceinline__ float rcp_f(float x) { return __builtin_amdgcn_rcpf(x); }

// write 4 activation slots for column c, 4 batches per lane (v pre-scaled by w).
// Trans budget/elem: 1 v_exp + 2 v_rcp.
// sigmoid = rcp(1+E), tanh = 2*rcp(1+E^2)-1  with E = exp(-v)  (robust at inf).
__device__ __forceinline__ void write_acts4(uint32_t* As, int c, int lane, float4 v) {
    *(uint2*)&As[(size_t)(0 * C + c) * 128 + 2 * lane] =
        make_uint2(pack2(v.x, v.y), pack2(v.z, v.w));
    *(uint2*)&As[(size_t)(1 * C + c) * 128 + 2 * lane] =
        make_uint2(pack2(fmaxf(v.x, 0.0f), fmaxf(v.y, 0.0f)),
                   pack2(fmaxf(v.z, 0.0f), fmaxf(v.w, 0.0f)));
    float ex = __expf(-v.x), ey = __expf(-v.y);
    float ez = __expf(-v.z), ew = __expf(-v.w);
    float tx = fmaf(2.0f, rcp_f(fmaf(ex, ex, 1.0f)), -1.0f);
    float ty = fmaf(2.0f, rcp_f(fmaf(ey, ey, 1.0f)), -1.0f);
    float tz = fmaf(2.0f, rcp_f(fmaf(ez, ez, 1.0f)), -1.0f);
    float tw = fmaf(2.0f, rcp_f(fmaf(ew, ew, 1.0f)), -1.0f);
    *(uint2*)&As[(size_t)(2 * C + c) * 128 + 2 * lane] =
        make_uint2(pack2(tx, ty), pack2(tz, tw));
    float sx = rcp_f(1.0f + ex), sy = rcp_f(1.0f + ey);
    float sz = rcp_f(1.0f + ez), sw = rcp_f(1.0f + ew);
    *(uint2*)&As[(size_t)(3 * C + c) * 128 + 2 * lane] =
        make_uint2(pack2(sx, sy), pack2(sz, sw));
}

// one slot: ds_read_b64 -> 2 bf16-pairs -> 2 v_pk_add_f32 (4 batches/lane)
#define SLOT_ACC(AB, R, S)                                                     \
    {                                                                          \
        uint2 q_ = *(const uint2*)&(AB)[(size_t)(S) * 128 + 2 * lane];         \
        v2f ua_, ub_;                                                          \
        ua_.x = __uint_as_float(q_.x << 16);                                   \
        ua_.y = __uint_as_float(q_.x & 0xFFFF0000u);                           \
        ub_.x = __uint_as_float(q_.y << 16);                                   \
        ub_.y = __uint_as_float(q_.y & 0xFFFF0000u);                           \
        accA[R] += ua_;                                                        \
        accB[R] += ub_;                                                        \
    }

// granule-2 row body for an overflow plane (mask bit r set)
#define OV_ROW(AB, MK, HARR, R)                                                \
    if ((MK) & (1u << (R))) {                                                  \
        uint32_t h_ = (HARR)[(R) >> 1];                                        \
        uint32_t u_ = ((R) & 1) ? (h_ >> 16) : h_;                             \
        SLOT_ACC(AB, R, u_ & 255u)                                             \
        SLOT_ACC(AB, R, (u_ >> 8) & 255u)                                      \
    }

// Planes 1-2 are straight-line with speculative scalar preload (words are
// always-valid pad-filled memory; use is guarded by W). Tail loop for W>3
// chunks only (~7%).
#define EDGE_PLANES(AB, SEGBASE, WVAL)                                         \
    {                                                                          \
        const uint32_t* sp_ = (SEGBASE);                                       \
        uint32_t mk1_ = sp_[8], mk2_ = sp_[17];                                \
        uint32_t h1_[8], h2_[8];                                               \
        _Pragma("unroll")                                                      \
        for (int i = 0; i < 8; i++) { h1_[i] = sp_[9 + i]; h2_[i] = sp_[18 + i]; } \
        _Pragma("unroll")                                                      \
        for (int i = 0; i < 8; i++) {                                          \
            uint32_t g = sp_[i];                                               \
            SLOT_ACC(AB, 2 * i,     g & 255u)                                  \
            SLOT_ACC(AB, 2 * i,     (g >> 8) & 255u)                           \
            SLOT_ACC(AB, 2 * i + 1, (g >> 16) & 255u)                          \
            SLOT_ACC(AB, 2 * i + 1, g >> 24)                                   \
        }                                                                      \
        if ((WVAL) > 1) {                                                      \
            _Pragma("unroll")                                                  \
            for (int r = 0; r < RB; r++) { OV_ROW(AB, mk1_, h1_, r) }          \
        }                                                                      \
        if ((WVAL) > 2) {                                                      \
            _Pragma("unroll")                                                  \
            for (int r = 0; r < RB; r++) { OV_ROW(AB, mk2_, h2_, r) }          \
        }                                                                      \
        _Pragma("unroll 1")                                                    \
        for (uint32_t p = 3; p < (WVAL); p++) {                                \
            const uint32_t* pp_ = sp_ + 8 + 9 * (p - 1);                       \
            uint32_t mk_ = pp_[0];                                             \
            _Pragma("unroll")                                                  \
            for (int r = 0; r < RB; r++) { OV_ROW(AB, mk_, pp_ + 1, r) }       \
        }                                                                      \
    }

// ---------------------------------------------------------------------------
// Stage 1: 16 waves x 16 rows = 256 rows; 256 batches per block.
// Grid (32 tiles, 8 row splits) = 256 blocks. LDS 2 x 64.5 KB (dbuf),
// ONE barrier per chunk; acts(ch+1) writes overlap edge(ch) reads.
// ---------------------------------------------------------------------------
__global__ __launch_bounds__(1024, 4) void k_hid(const float* __restrict__ x_t,
                                                 const float* __restrict__ wp,
                                                 const uint32_t* __restrict__ seg1,
                                                 const uint32_t* __restrict__ hdr1,
                                                 __hip_bfloat16* __restrict__ hidden_t) {
    __shared__ uint32_t As[2 * ABUF_U32];       // 129 KB

    const float w  = wp[0];
    const int tile = blockIdx.x;                // 0..31
    const int lane = threadIdx.x & 63;
    const int wv   = __builtin_amdgcn_readfirstlane(threadIdx.x >> 6); // 0..15
    const int rb   = blockIdx.y * 16 + wv;      // row-block 0..127
    const int b0   = tile * BT;

    if (threadIdx.x < 128) {                    // both zero pages
        As[ZSLOT * 128 + threadIdx.x] = 0u;
        As[ABUF_U32 + ZSLOT * 128 + threadIdx.x] = 0u;
    }

    v2f accA[RB], accB[RB];
    #pragma unroll
    for (int r = 0; r < RB; r++) {
        accA[r] = (v2f)0.0f;
        accB[r] = (v2f)0.0f;
    }

    // prologue: acts(0) into buf0; prefetch v for chunk 1
    float4 v[2];
    #pragma unroll
    for (int j = 0; j < 2; j++) {
        int gcol = wv * 2 + j;
        const float2* xp = (const float2*)&x_t[(size_t)gcol * BATCH + b0];
        float2 u0 = xp[lane], u1 = xp[64 + lane];
        v[j] = make_float4(w * u0.x, w * u0.y, w * u1.x, w * u1.y);
    }
    write_acts4(As, wv * 2 + 0, lane, v[0]);
    write_acts4(As, wv * 2 + 1, lane, v[1]);
    #pragma unroll
    for (int j = 0; j < 2; j++) {
        int gcol = C + wv * 2 + j;
        const float2* xp = (const float2*)&x_t[(size_t)gcol * BATCH + b0];
        float2 u0 = xp[lane], u1 = xp[64 + lane];
        v[j] = make_float4(w * u0.x, w * u0.y, w * u1.x, w * u1.y);
    }
    __syncthreads();

    #pragma unroll 1
    for (int ch = 0; ch < S1_CH; ch++) {
        uint32_t* cur = As + (size_t)(ch & 1) * ABUF_U32;
        uint32_t* nxt = As + (size_t)((ch + 1) & 1) * ABUF_U32;
        if (ch + 1 < S1_CH) {
            write_acts4(nxt, wv * 2 + 0, lane, v[0]);
            write_acts4(nxt, wv * 2 + 1, lane, v[1]);
            if (ch + 2 < S1_CH) {
                #pragma unroll
                for (int j = 0; j < 2; j++) {
                    int gcol = (ch + 2) * C + wv * 2 + j;
                    const float2* xp = (const float2*)&x_t[(size_t)gcol * BATCH + b0];
                    float2 u0 = xp[lane], u1 = xp[64 + lane];
                    v[j] = make_float4(w * u0.x, w * u0.y, w * u1.x, w * u1.y);
                }
            }
        }
        int sidx = rb * S1_CH + ch;
        uint32_t W = hdr1[sidx];
        EDGE_PLANES(cur, seg1 + (size_t)sidx * SEG_U32, W)
        __syncthreads();                        // acts(ch+1) ready; edge(ch) drained
    }

    const int row0 = rb * RB;
    #pragma unroll
    for (int r = 0; r < RB; r++) {
        *(uint32_t*)&hidden_t[(size_t)(row0 + r) * BATCH + b0 + 2 * lane] =
            pack2(accA[r].x, accA[r].y);
        *(uint32_t*)&hidden_t[(size_t)(row0 + r) * BATCH + b0 + 128 + 2 * lane] =
            pack2(accB[r].x, accB[r].y);
    }
}

// source loader for stage 2 (x_t fp32 or hidden_t bf16), pre-scaled by w
__device__ __forceinline__ float4 load_src4(const float* __restrict__ x_t,
                                            const __hip_bfloat16* __restrict__ hidden_t,
                                            int gcol, int b0, int lane, float w) {
    if (gcol < IN_DIM) {
        const float2* xp = (const float2*)&x_t[(size_t)gcol * BATCH + b0];
        float2 u0 = xp[lane], u1 = xp[64 + lane];
        return make_float4(w * u0.x, w * u0.y, w * u1.x, w * u1.y);
    } else {
        const uint16_t* hp = (const uint16_t*)&hidden_t[(size_t)(gcol - IN_DIM) * BATCH + b0];
        uint32_t q0 = *(const uint32_t*)&hp[2 * lane];
        uint32_t q1 = *(const uint32_t*)&hp[128 + 2 * lane];
        return make_float4(w * __uint_as_float(q0 << 16),
                           w * __uint_as_float(q0 & 0xFFFF0000u),
                           w * __uint_as_float(q1 << 16),
                           w * __uint_as_float(q1 & 0xFFFF0000u));
    }
}

// ---------------------------------------------------------------------------
// Stage 2: 16 waves x 16 rows = ALL 256 out rows; 256 batches per block.
// Grid (32 tiles, 8 chunk groups of 12) = 256 blocks. Dbuf as in k_hid.
// ---------------------------------------------------------------------------
__global__ __launch_bounds__(1024, 4) void k_out(const float* __restrict__ x_t,
                                                 const __hip_bfloat16* __restrict__ hidden_t,
                                                 const float* __restrict__ wp,
                                                 const uint32_t* __restrict__ seg2,
                                                 const uint32_t* __restrict__ hdr2,
                                                 float* __restrict__ partials) {
    __shared__ uint32_t As[2 * ABUF_U32];

    const float w  = wp[0];
    const int tile = blockIdx.x;                // 0..31
    const int cg   = blockIdx.y;                // 0..7
    const int lane = threadIdx.x & 63;
    const int wv   = __builtin_amdgcn_readfirstlane(threadIdx.x >> 6); // 0..15
    const int b0   = tile * BT;

    if (threadIdx.x < 128) {
        As[ZSLOT * 128 + threadIdx.x] = 0u;
        As[ABUF_U32 + ZSLOT * 128 + threadIdx.x] = 0u;
    }

    v2f accA[RB], accB[RB];
    #pragma unroll
    for (int r = 0; r < RB; r++) {
        accA[r] = (v2f)0.0f;
        accB[r] = (v2f)0.0f;
    }

    float4 v[2];
    #pragma unroll
    for (int j = 0; j < 2; j++)
        v[j] = load_src4(x_t, hidden_t, (cg * 12) * C + wv * 2 + j, b0, lane, w);
    write_acts4(As, wv * 2 + 0, lane, v[0]);
    write_acts4(As, wv * 2 + 1, lane, v[1]);
    #pragma unroll
    for (int j = 0; j < 2; j++)
        v[j] = load_src4(x_t, hidden_t, (cg * 12 + 1) * C + wv * 2 + j, b0, lane, w);
    __syncthreads();

    #pragma unroll 1
    for (int cj = 0; cj < 12; cj++) {
        int ch = cg * 12 + cj;
        uint32_t* cur = As + (size_t)(cj & 1) * ABUF_U32;
        uint32_t* nxt = As + (size_t)((cj + 1) & 1) * ABUF_U32;
        if (cj + 1 < 12) {
            write_acts4(nxt, wv * 2 + 0, lane, v[0]);
            write_acts4(nxt, wv * 2 + 1, lane, v[1]);
            if (cj + 2 < 12) {
                #pragma unroll
                for (int j = 0; j < 2; j++)
                    v[j] = load_src4(x_t, hidden_t, (ch + 2) * C + wv * 2 + j, b0, lane, w);
            }
        }
        int sidx = wv * S2_CH + ch;              // wv = row-block 0..15
        uint32_t W = hdr2[sidx];
        EDGE_PLANES(cur, seg2 + (size_t)sidx * SEG_U32, W)
        __syncthreads();
    }

    #pragma unroll
    for (int r = 0; r < RB; r++) {
        size_t base = ((size_t)cg * OUT_DIM + wv * RB + r) * BATCH + b0;
        *(v2f*)&partials[base + 2 * lane]       = accA[r];
        *(v2f*)&partials[base + 128 + 2 * lane] = accB[r];
    }
}

// ---------------------------------------------------------------------------
// k_sum: reduce 8 partial planes + transpose [r][b] -> out[b][r] (float4).
// ---------------------------------------------------------------------------
__global__ __launch_bounds__(256) void k_sum(const float* __restrict__ partials,
                                             float* __restrict__ out) {
    __shared__ float t[16][65];
    const int b0 = blockIdx.x * 64, r0 = blockIdx.y * 16;
    const int lane = threadIdx.x & 63;
    const int g4   = threadIdx.x >> 6;

    #pragma unroll
    for (int k = 0; k < 4; k++) {
        int rr = g4 * 4 + k;
        float s = 0.0f;
        #pragma unroll
        for (int cg = 0; cg < 8; cg++)
            s += partials[((size_t)cg * OUT_DIM + r0 + rr) * BATCH + b0 + lane];
        t[rr][lane] = s;
    }
    __syncthreads();
    int bb = threadIdx.x >> 2, rq = threadIdx.x & 3;
    float4 v;
    v.x = t[rq * 4 + 0][bb];
    v.y = t[rq * 4 + 1][bb];
    v.z = t[rq * 4 + 2][bb];
    v.w = t[rq * 4 + 3][bb];
    *(float4*)&out[(size_t)(b0 + bb) * OUT_DIM + r0 + rq * 4] = v;
}

// ---------------------------------------------------------------------------
extern "C" void kernel_launch(void* const* d_in, const int* in_sizes, int n_in,
                              void* d_out, int out_size, void* d_ws, size_t ws_size,
                              hipStream_t stream) {
    const float* x   = (const float*)d_in[0];
    const float* w   = (const float*)d_in[1];
    const int*   mat = (const int*)d_in[2];
    float* out = (float*)d_out;

    uint8_t* ws = (uint8_t*)d_ws;
    size_t off = 0;
    __hip_bfloat16* hidden_t = (__hip_bfloat16*)(ws + off); off += (size_t)BATCH * N_HID * 2;  // 33.6 MB
    float* x_t = (float*)(ws + off);        off += (size_t)IN_DIM * BATCH * 4;                 // 33.6 MB
    uint32_t* seg1 = (uint32_t*)(ws + off); off += (size_t)NSEG1 * SEG_U32 * 4;                //  2.62 MB
    uint32_t* seg2 = (uint32_t*)(ws + off); off += (size_t)NSEG2 * SEG_U32 * 4;                //  0.98 MB
    uint32_t* hdr1 = (uint32_t*)(ws + off); off += (size_t)NSEG1 * 4;
    uint32_t* hdr2 = (uint32_t*)(ws + off); off += (size_t)NSEG2 * 4;
    float* partials = (float*)(ws + off);   off += (size_t)8 * OUT_DIM * BATCH * 4;            // 67.1 MB
    (void)ws_size; (void)in_sizes; (void)n_in; (void)out_size;

    hipMemsetAsync(seg1, 0x80, (size_t)(NSEG1 + NSEG2) * SEG_U32 * 4, stream);

    {
        int nseg = NSEG1 + NSEG2;                   // 5632 waves
        k_prep<<<(nseg + 3) / 4, 256, 0, stream>>>(mat, seg1, seg2, hdr1, hdr2);
    }
    {
        dim3 g(BATCH / 64, IN_DIM / 64);            // 128 x 16
        k_xt<<<g, 256, 0, stream>>>(x, x_t);
    }
    {
        dim3 g(BATCH / BT, 8);                      // 32 x 8 = 256 blocks
        k_hid<<<g, 1024, 0, stream>>>(x_t, w, seg1, hdr1, hidden_t);
    }
    {
        dim3 g(BATCH / BT, 8);                      // 32 x 8 = 256 blocks
        k_out<<<g, 1024, 0, stream>>>(x_t, hidden_t, w, seg2, hdr2, partials);
    }
    {
        dim3 g(BATCH / 64, OUT_DIM / 16);           // 2048 blocks
        k_sum<<<g, 256, 0, stream>>>(partials, out);
    }
}

// Round 5
// 357.609 us; speedup vs baseline: 43.0084x; 43.0084x over previous
//
#include <hip/hip_runtime.h>
#include <hip/hip_bf16.h>
#include <stdint.h>

// Problem constants
#define BATCH   8192
#define IN_DIM  1024
#define N_HID   2048
#define OUT_DIM 256
#define SRC_DIM 3072

// Tiling
#define C     32                   // source columns per chunk
#define RB    16                   // rows per row-block (= rows per wave)
#define BT    256                  // batch per block (4/lane: 2l,2l+1,128+2l,128+2l+1)
#define S1_CH (IN_DIM / C)         // 32
#define S1_RB (N_HID / RB)         // 128
#define S2_CH (SRC_DIM / C)        // 96
#define S2_RB (OUT_DIM / RB)       // 16
#define NSEG1 (S1_RB * S1_CH)      // 4096
#define NSEG2 (S2_RB * S2_CH)      // 1536
#define ZSLOT 128                  // A-tile zero page (pad byte 0x80)
#define SEG_U32 160                // segment stride (640 B; max 15 overflow planes)
#define ABUF_U32 ((4 * C + 1) * 128)  // 16512 u32 = 64.5 KB per A-tile buffer

// Segment format v5 (granule-2 overflow; plane-0 identical to proven v3):
//   u32[0..7]   plane-0: row r -> u16 at byte 2r (2 slot bytes, pad 0x80)
//   overflow planes p=1..15 at u32 8+9(p-1), stride 9:
//     [0]    = 16-bit row mask (rows with n > 2p)
//     [1..8] = u16 per row: 2 slot bytes for overflow idx 2(p-1), 2(p-1)+1
//   hdr: W = total planes, wave-uniform.
// R1 LESSON: per-slot vector gating costs ~70 VALU/slot; plane-0 stays
// unconditional, pads hit the zero page.
// R2 LESSON: BT=256 halved per-element VALU; 1 block/CU exposes skew.
// R3 LESSON: dbuf + 1 barrier/chunk recovered most skew (206->157).
// R4 LESSON (9297us!): speculative h1_[8]/h2_[8] preload arrays blew the
// 128-VGPR cap (launch_bounds 1024,4); allocator spilled the ACCUMULATORS
// -> every slot op became a scratch RMW (32 GB WRITE_SIZE, VALU 1.9%).
// Slot words must be loaded INSIDE the mask guard, used immediately.

// ---------------------------------------------------------------------------
__global__ void k_prep(const int* __restrict__ mat,
                       uint32_t* __restrict__ seg1, uint32_t* __restrict__ seg2,
                       uint32_t* __restrict__ hdr1, uint32_t* __restrict__ hdr2) {
    int wid  = (blockIdx.x * blockDim.x + threadIdx.x) >> 6;
    int lane = threadIdx.x & 63;
    if (wid >= NSEG1 + NSEG2) return;

    int row0, col0;
    uint32_t *seg, *hdr;
    if (wid < NSEG1) {
        int rb = wid / S1_CH, ch = wid % S1_CH;
        row0 = rb * RB;          col0 = ch * C;
        seg = seg1 + (size_t)wid * SEG_U32;  hdr = hdr1 + wid;
    } else {
        int s  = wid - NSEG1;
        int rb = s / S2_CH, ch = s % S2_CH;
        row0 = N_HID + rb * RB;  col0 = ch * C;
        seg = seg2 + (size_t)s * SEG_U32;    hdr = hdr2 + s;
    }

    int n = 0;
    if (lane < RB) {
        const int* mrow = mat + (size_t)(row0 + lane) * SRC_DIM + col0;
        uint8_t* sb = (uint8_t*)seg;
        for (int c = 0; c < C; c++) {
            int code = mrow[c];
            if (code != 0) {
                uint8_t slot = (uint8_t)((code - 1) * C + c);
                if (n < 2) {
                    sb[2 * lane + n] = slot;               // plane-0 u16
                } else {
                    int j  = n - 2;                        // overflow index
                    int pl = j >> 1;                       // 0-based overflow plane
                    sb[(size_t)(8 + 9 * pl + 1 + (lane >> 1)) * 4
                       + (lane & 1) * 2 + (j & 1)] = slot;
                }
                n++;
            }
        }
    }
    int m = n;
    #pragma unroll
    for (int d = 1; d < 64; d <<= 1) m = max(m, __shfl_xor(m, d));
    uint32_t Wv = (m <= 2) ? 1u : 1u + (uint32_t)((m - 1) >> 1);

    for (uint32_t p = 1; p < Wv; p++) {
        unsigned long long b = __ballot(n > (int)(2 * p));
        if (lane == 0) seg[8 + 9 * (p - 1)] = (uint32_t)(b & 0xFFFFu);
    }
    if (lane == 0) *hdr = Wv;
}

// ---------------------------------------------------------------------------
// k_xt: transpose x[8192][1024] -> x_t[1024][8192] (fp32), 64x64 LDS tiles.
// ---------------------------------------------------------------------------
__global__ __launch_bounds__(256) void k_xt(const float* __restrict__ x,
                                            float* __restrict__ x_t) {
    __shared__ float t[64][65];
    const int b0 = blockIdx.x * 64, c0 = blockIdx.y * 64;
    {
        int r  = threadIdx.x >> 4;
        int cq = (threadIdx.x & 15) * 4;
        #pragma unroll
        for (int k = 0; k < 4; k++) {
            int rr = r + 16 * k;
            float4 v = *(const float4*)&x[(size_t)(b0 + rr) * IN_DIM + c0 + cq];
            t[rr][cq + 0] = v.x; t[rr][cq + 1] = v.y;
            t[rr][cq + 2] = v.z; t[rr][cq + 3] = v.w;
        }
    }
    __syncthreads();
    {
        int bq  = (threadIdx.x & 15) * 4;
        int cc0 = threadIdx.x >> 4;
        #pragma unroll
        for (int k = 0; k < 4; k++) {
            int cc = cc0 + 16 * k;
            float4 v;
            v.x = t[bq + 0][cc]; v.y = t[bq + 1][cc];
            v.z = t[bq + 2][cc]; v.w = t[bq + 3][cc];
            *(float4*)&x_t[(size_t)(c0 + cc) * BATCH + b0 + bq] = v;
        }
    }
}

typedef float v2f __attribute__((ext_vector_type(2)));

// pack two floats as bf16 pair: low16 = first, high16 = second
__device__ __forceinline__ uint32_t pack2(float a, float b) {
    __hip_bfloat162 h = __float22bfloat162_rn(make_float2(a, b));
    union { __hip_bfloat162 h2; uint32_t u; } u;
    u.h2 = h;
    return u.u;
}

__device__ __forceinline__ float rcp_f(float x) { return __builtin_amdgcn_rcpf(x); }

// write 4 activation slots for column c, 4 batches per lane (v pre-scaled by w).
// Trans budget/elem: 1 v_exp + 2 v_rcp.
// sigmoid = rcp(1+E), tanh = 2*rcp(1+E^2)-1  with E = exp(-v)  (robust at inf).
__device__ __forceinline__ void write_acts4(uint32_t* As, int c, int lane, float4 v) {
    *(uint2*)&As[(size_t)(0 * C + c) * 128 + 2 * lane] =
        make_uint2(pack2(v.x, v.y), pack2(v.z, v.w));
    *(uint2*)&As[(size_t)(1 * C + c) * 128 + 2 * lane] =
        make_uint2(pack2(fmaxf(v.x, 0.0f), fmaxf(v.y, 0.0f)),
                   pack2(fmaxf(v.z, 0.0f), fmaxf(v.w, 0.0f)));
    float ex = __expf(-v.x), ey = __expf(-v.y);
    float ez = __expf(-v.z), ew = __expf(-v.w);
    float tx = fmaf(2.0f, rcp_f(fmaf(ex, ex, 1.0f)), -1.0f);
    float ty = fmaf(2.0f, rcp_f(fmaf(ey, ey, 1.0f)), -1.0f);
    float tz = fmaf(2.0f, rcp_f(fmaf(ez, ez, 1.0f)), -1.0f);
    float tw = fmaf(2.0f, rcp_f(fmaf(ew, ew, 1.0f)), -1.0f);
    *(uint2*)&As[(size_t)(2 * C + c) * 128 + 2 * lane] =
        make_uint2(pack2(tx, ty), pack2(tz, tw));
    float sx = rcp_f(1.0f + ex), sy = rcp_f(1.0f + ey);
    float sz = rcp_f(1.0f + ez), sw = rcp_f(1.0f + ew);
    *(uint2*)&As[(size_t)(3 * C + c) * 128 + 2 * lane] =
        make_uint2(pack2(sx, sy), pack2(sz, sw));
}

// one slot: ds_read_b64 -> 2 bf16-pairs -> 2 v_pk_add_f32 (4 batches/lane)
#define SLOT_ACC(AB, R, S)                                                     \
    {                                                                          \
        uint2 q_ = *(const uint2*)&(AB)[(size_t)(S) * 128 + 2 * lane];         \
        v2f ua_, ub_;                                                          \
        ua_.x = __uint_as_float(q_.x << 16);                                   \
        ua_.y = __uint_as_float(q_.x & 0xFFFF0000u);                           \
        ub_.x = __uint_as_float(q_.y << 16);                                   \
        ub_.y = __uint_as_float(q_.y & 0xFFFF0000u);                           \
        accA[R] += ua_;                                                        \
        accB[R] += ub_;                                                        \
    }

// R3-proven structure: per-plane loop, wave-uniform scalar mask branch,
// slot word loaded INSIDE the guard and used immediately (no live arrays).
#define EDGE_PLANES(AB, SEGBASE, WVAL)                                         \
    {                                                                          \
        const uint32_t* sp_ = (SEGBASE);                                       \
        _Pragma("unroll")                                                      \
        for (int i = 0; i < 8; i++) {                                          \
            uint32_t g = sp_[i];                                               \
            SLOT_ACC(AB, 2 * i,     g & 255u)                                  \
            SLOT_ACC(AB, 2 * i,     (g >> 8) & 255u)                           \
            SLOT_ACC(AB, 2 * i + 1, (g >> 16) & 255u)                          \
            SLOT_ACC(AB, 2 * i + 1, g >> 24)                                   \
        }                                                                      \
        _Pragma("unroll 1")                                                    \
        for (uint32_t p = 1; p < (WVAL); p++) {                                \
            const uint32_t* pp_ = sp_ + 8 + 9 * (p - 1);                       \
            uint32_t mask = pp_[0];                                            \
            _Pragma("unroll")                                                  \
            for (int r = 0; r < RB; r++) {                                     \
                if (mask & (1u << r)) {                                        \
                    uint32_t h_ = pp_[1 + (r >> 1)];                           \
                    uint32_t u_ = (r & 1) ? (h_ >> 16) : h_;                   \
                    SLOT_ACC(AB, r, u_ & 255u)                                 \
                    SLOT_ACC(AB, r, (u_ >> 8) & 255u)                          \
                }                                                              \
            }                                                                  \
        }                                                                      \
    }

// ---------------------------------------------------------------------------
// Stage 1: 16 waves x 16 rows = 256 rows; 256 batches per block.
// Grid (32 tiles, 8 row splits) = 256 blocks. LDS 2 x 64.5 KB (dbuf),
// ONE barrier per chunk; acts(ch+1) writes overlap edge(ch) reads.
// ---------------------------------------------------------------------------
__global__ __launch_bounds__(1024, 4) void k_hid(const float* __restrict__ x_t,
                                                 const float* __restrict__ wp,
                                                 const uint32_t* __restrict__ seg1,
                                                 const uint32_t* __restrict__ hdr1,
                                                 __hip_bfloat16* __restrict__ hidden_t) {
    __shared__ uint32_t As[2 * ABUF_U32];       // 129 KB

    const float w  = wp[0];
    const int tile = blockIdx.x;                // 0..31
    const int lane = threadIdx.x & 63;
    const int wv   = __builtin_amdgcn_readfirstlane(threadIdx.x >> 6); // 0..15
    const int rb   = blockIdx.y * 16 + wv;      // row-block 0..127
    const int b0   = tile * BT;

    if (threadIdx.x < 128) {                    // both zero pages
        As[ZSLOT * 128 + threadIdx.x] = 0u;
        As[ABUF_U32 + ZSLOT * 128 + threadIdx.x] = 0u;
    }

    v2f accA[RB], accB[RB];
    #pragma unroll
    for (int r = 0; r < RB; r++) {
        accA[r] = (v2f)0.0f;
        accB[r] = (v2f)0.0f;
    }

    // prologue: acts(0) into buf0; prefetch v for chunk 1
    float4 v[2];
    #pragma unroll
    for (int j = 0; j < 2; j++) {
        int gcol = wv * 2 + j;
        const float2* xp = (const float2*)&x_t[(size_t)gcol * BATCH + b0];
        float2 u0 = xp[lane], u1 = xp[64 + lane];
        v[j] = make_float4(w * u0.x, w * u0.y, w * u1.x, w * u1.y);
    }
    write_acts4(As, wv * 2 + 0, lane, v[0]);
    write_acts4(As, wv * 2 + 1, lane, v[1]);
    #pragma unroll
    for (int j = 0; j < 2; j++) {
        int gcol = C + wv * 2 + j;
        const float2* xp = (const float2*)&x_t[(size_t)gcol * BATCH + b0];
        float2 u0 = xp[lane], u1 = xp[64 + lane];
        v[j] = make_float4(w * u0.x, w * u0.y, w * u1.x, w * u1.y);
    }
    __syncthreads();

    #pragma unroll 1
    for (int ch = 0; ch < S1_CH; ch++) {
        uint32_t* cur = As + (size_t)(ch & 1) * ABUF_U32;
        uint32_t* nxt = As + (size_t)((ch + 1) & 1) * ABUF_U32;
        if (ch + 1 < S1_CH) {
            write_acts4(nxt, wv * 2 + 0, lane, v[0]);
            write_acts4(nxt, wv * 2 + 1, lane, v[1]);
            if (ch + 2 < S1_CH) {
                #pragma unroll
                for (int j = 0; j < 2; j++) {
                    int gcol = (ch + 2) * C + wv * 2 + j;
                    const float2* xp = (const float2*)&x_t[(size_t)gcol * BATCH + b0];
                    float2 u0 = xp[lane], u1 = xp[64 + lane];
                    v[j] = make_float4(w * u0.x, w * u0.y, w * u1.x, w * u1.y);
                }
            }
        }
        int sidx = rb * S1_CH + ch;
        uint32_t W = hdr1[sidx];
        EDGE_PLANES(cur, seg1 + (size_t)sidx * SEG_U32, W)
        __syncthreads();                        // acts(ch+1) ready; edge(ch) drained
    }

    const int row0 = rb * RB;
    #pragma unroll
    for (int r = 0; r < RB; r++) {
        *(uint32_t*)&hidden_t[(size_t)(row0 + r) * BATCH + b0 + 2 * lane] =
            pack2(accA[r].x, accA[r].y);
        *(uint32_t*)&hidden_t[(size_t)(row0 + r) * BATCH + b0 + 128 + 2 * lane] =
            pack2(accB[r].x, accB[r].y);
    }
}

// source loader for stage 2 (x_t fp32 or hidden_t bf16), pre-scaled by w
__device__ __forceinline__ float4 load_src4(const float* __restrict__ x_t,
                                            const __hip_bfloat16* __restrict__ hidden_t,
                                            int gcol, int b0, int lane, float w) {
    if (gcol < IN_DIM) {
        const float2* xp = (const float2*)&x_t[(size_t)gcol * BATCH + b0];
        float2 u0 = xp[lane], u1 = xp[64 + lane];
        return make_float4(w * u0.x, w * u0.y, w * u1.x, w * u1.y);
    } else {
        const uint16_t* hp = (const uint16_t*)&hidden_t[(size_t)(gcol - IN_DIM) * BATCH + b0];
        uint32_t q0 = *(const uint32_t*)&hp[2 * lane];
        uint32_t q1 = *(const uint32_t*)&hp[128 + 2 * lane];
        return make_float4(w * __uint_as_float(q0 << 16),
                           w * __uint_as_float(q0 & 0xFFFF0000u),
                           w * __uint_as_float(q1 << 16),
                           w * __uint_as_float(q1 & 0xFFFF0000u));
    }
}

// ---------------------------------------------------------------------------
// Stage 2: 16 waves x 16 rows = ALL 256 out rows; 256 batches per block.
// Grid (32 tiles, 8 chunk groups of 12) = 256 blocks. Dbuf as in k_hid.
// ---------------------------------------------------------------------------
__global__ __launch_bounds__(1024, 4) void k_out(const float* __restrict__ x_t,
                                                 const __hip_bfloat16* __restrict__ hidden_t,
                                                 const float* __restrict__ wp,
                                                 const uint32_t* __restrict__ seg2,
                                                 const uint32_t* __restrict__ hdr2,
                                                 float* __restrict__ partials) {
    __shared__ uint32_t As[2 * ABUF_U32];

    const float w  = wp[0];
    const int tile = blockIdx.x;                // 0..31
    const int cg   = blockIdx.y;                // 0..7
    const int lane = threadIdx.x & 63;
    const int wv   = __builtin_amdgcn_readfirstlane(threadIdx.x >> 6); // 0..15
    const int b0   = tile * BT;

    if (threadIdx.x < 128) {
        As[ZSLOT * 128 + threadIdx.x] = 0u;
        As[ABUF_U32 + ZSLOT * 128 + threadIdx.x] = 0u;
    }

    v2f accA[RB], accB[RB];
    #pragma unroll
    for (int r = 0; r < RB; r++) {
        accA[r] = (v2f)0.0f;
        accB[r] = (v2f)0.0f;
    }

    float4 v[2];
    #pragma unroll
    for (int j = 0; j < 2; j++)
        v[j] = load_src4(x_t, hidden_t, (cg * 12) * C + wv * 2 + j, b0, lane, w);
    write_acts4(As, wv * 2 + 0, lane, v[0]);
    write_acts4(As, wv * 2 + 1, lane, v[1]);
    #pragma unroll
    for (int j = 0; j < 2; j++)
        v[j] = load_src4(x_t, hidden_t, (cg * 12 + 1) * C + wv * 2 + j, b0, lane, w);
    __syncthreads();

    #pragma unroll 1
    for (int cj = 0; cj < 12; cj++) {
        int ch = cg * 12 + cj;
        uint32_t* cur = As + (size_t)(cj & 1) * ABUF_U32;
        uint32_t* nxt = As + (size_t)((cj + 1) & 1) * ABUF_U32;
        if (cj + 1 < 12) {
            write_acts4(nxt, wv * 2 + 0, lane, v[0]);
            write_acts4(nxt, wv * 2 + 1, lane, v[1]);
            if (cj + 2 < 12) {
                #pragma unroll
                for (int j = 0; j < 2; j++)
                    v[j] = load_src4(x_t, hidden_t, (ch + 2) * C + wv * 2 + j, b0, lane, w);
            }
        }
        int sidx = wv * S2_CH + ch;              // wv = row-block 0..15
        uint32_t W = hdr2[sidx];
        EDGE_PLANES(cur, seg2 + (size_t)sidx * SEG_U32, W)
        __syncthreads();
    }

    #pragma unroll
    for (int r = 0; r < RB; r++) {
        size_t base = ((size_t)cg * OUT_DIM + wv * RB + r) * BATCH + b0;
        *(v2f*)&partials[base + 2 * lane]       = accA[r];
        *(v2f*)&partials[base + 128 + 2 * lane] = accB[r];
    }
}

// ---------------------------------------------------------------------------
// k_sum: reduce 8 partial planes + transpose [r][b] -> out[b][r] (float4).
// ---------------------------------------------------------------------------
__global__ __launch_bounds__(256) void k_sum(const float* __restrict__ partials,
                                             float* __restrict__ out) {
    __shared__ float t[16][65];
    const int b0 = blockIdx.x * 64, r0 = blockIdx.y * 16;
    const int lane = threadIdx.x & 63;
    const int g4   = threadIdx.x >> 6;

    #pragma unroll
    for (int k = 0; k < 4; k++) {
        int rr = g4 * 4 + k;
        float s = 0.0f;
        #pragma unroll
        for (int cg = 0; cg < 8; cg++)
            s += partials[((size_t)cg * OUT_DIM + r0 + rr) * BATCH + b0 + lane];
        t[rr][lane] = s;
    }
    __syncthreads();
    int bb = threadIdx.x >> 2, rq = threadIdx.x & 3;
    float4 v;
    v.x = t[rq * 4 + 0][bb];
    v.y = t[rq * 4 + 1][bb];
    v.z = t[rq * 4 + 2][bb];
    v.w = t[rq * 4 + 3][bb];
    *(float4*)&out[(size_t)(b0 + bb) * OUT_DIM + r0 + rq * 4] = v;
}

// ---------------------------------------------------------------------------
extern "C" void kernel_launch(void* const* d_in, const int* in_sizes, int n_in,
                              void* d_out, int out_size, void* d_ws, size_t ws_size,
                              hipStream_t stream) {
    const float* x   = (const float*)d_in[0];
    const float* w   = (const float*)d_in[1];
    const int*   mat = (const int*)d_in[2];
    float* out = (float*)d_out;

    uint8_t* ws = (uint8_t*)d_ws;
    size_t off = 0;
    __hip_bfloat16* hidden_t = (__hip_bfloat16*)(ws + off); off += (size_t)BATCH * N_HID * 2;  // 33.6 MB
    float* x_t = (float*)(ws + off);        off += (size_t)IN_DIM * BATCH * 4;                 // 33.6 MB
    uint32_t* seg1 = (uint32_t*)(ws + off); off += (size_t)NSEG1 * SEG_U32 * 4;                //  2.62 MB
    uint32_t* seg2 = (uint32_t*)(ws + off); off += (size_t)NSEG2 * SEG_U32 * 4;                //  0.98 MB
    uint32_t* hdr1 = (uint32_t*)(ws + off); off += (size_t)NSEG1 * 4;
    uint32_t* hdr2 = (uint32_t*)(ws + off); off += (size_t)NSEG2 * 4;
    float* partials = (float*)(ws + off);   off += (size_t)8 * OUT_DIM * BATCH * 4;            // 67.1 MB
    (void)ws_size; (void)in_sizes; (void)n_in; (void)out_size;

    hipMemsetAsync(seg1, 0x80, (size_t)(NSEG1 + NSEG2) * SEG_U32 * 4, stream);

    {
        int nseg = NSEG1 + NSEG2;                   // 5632 waves
        k_prep<<<(nseg + 3) / 4, 256, 0, stream>>>(mat, seg1, seg2, hdr1, hdr2);
    }
    {
        dim3 g(BATCH / 64, IN_DIM / 64);            // 128 x 16
        k_xt<<<g, 256, 0, stream>>>(x, x_t);
    }
    {
        dim3 g(BATCH / BT, 8);                      // 32 x 8 = 256 blocks
        k_hid<<<g, 1024, 0, stream>>>(x_t, w, seg1, hdr1, hidden_t);
    }
    {
        dim3 g(BATCH / BT, 8);                      // 32 x 8 = 256 blocks
        k_out<<<g, 1024, 0, stream>>>(x_t, hidden_t, w, seg2, hdr2, partials);
    }
    {
        dim3 g(BATCH / 64, OUT_DIM / 16);           // 2048 blocks
        k_sum<<<g, 256, 0, stream>>>(partials, out);
    }
}

// Round 6
// 353.461 us; speedup vs baseline: 43.5131x; 1.0117x over previous
//
#include <hip/hip_runtime.h>
#include <hip/hip_bf16.h>
#include <stdint.h>

// Problem constants
#define BATCH   8192
#define IN_DIM  1024
#define N_HID   2048
#define OUT_DIM 256
#define SRC_DIM 3072

// Tiling
#define C     32                   // source columns per chunk
#define RB    16                   // rows per row-block (= rows per wave)
#define BT    256                  // batch per block (4/lane: 2l,2l+1,128+2l,128+2l+1)
#define S1_CH (IN_DIM / C)         // 32
#define S1_RB (N_HID / RB)         // 128
#define S2_CH (SRC_DIM / C)        // 96
#define S2_RB (OUT_DIM / RB)       // 16
#define NSEG1 (S1_RB * S1_CH)      // 4096
#define NSEG2 (S2_RB * S2_CH)      // 1536
#define ZSLOT 128                  // A-tile zero page (pad byte 0x80)
#define SEG_U32 160                // segment stride (640 B; max 15 overflow planes)
#define ABUF_U32 ((4 * C + 1) * 128)  // 16512 u32 = 64.5 KB per A-tile buffer

// Segment format v5 (granule-2 overflow; plane-0 identical to proven v3):
//   u32[0..7]   plane-0: row r -> u16 at byte 2r (2 slot bytes, pad 0x80)
//   overflow planes p=1..15 at u32 8+9(p-1), stride 9:
//     [0]    = 16-bit row mask (rows with n > 2p)
//     [1..8] = u16 per row: 2 slot bytes for overflow idx 2(p-1), 2(p-1)+1
//   hdr: W = total planes, wave-uniform.
// R1 LESSON: per-slot vector gating costs ~70 VALU/slot; plane-0 stays
// unconditional, pads hit the zero page.
// R2 LESSON: BT=256 halved per-element VALU; 1 block/CU exposes skew.
// R3 LESSON: dbuf + 1 barrier/chunk recovered most skew (206->157).
// R4 LESSON (9297us!): speculative preload arrays blew the 128-VGPR cap;
// allocator spilled the ACCUMULATORS. Slot words load INSIDE guards.
// R5 AUDIT: VALUBusy implies ~880 instr/wave-chunk vs ~390 modeled ->
// segment words were VECTOR loads; W/mask in VGPR => vector plane loop,
// exec-mask churn per row test, extracts on VALU.
// R6: READFIRSTLANE-SCALARIZE all segment words -> SALU control + extracts
// (idle pipe, dual-issues with VALU), uniform s_cbranch gating.

#define RFL(x) __builtin_amdgcn_readfirstlane((uint32_t)(x))

// ---------------------------------------------------------------------------
__global__ void k_prep(const int* __restrict__ mat,
                       uint32_t* __restrict__ seg1, uint32_t* __restrict__ seg2,
                       uint32_t* __restrict__ hdr1, uint32_t* __restrict__ hdr2) {
    int wid  = (blockIdx.x * blockDim.x + threadIdx.x) >> 6;
    int lane = threadIdx.x & 63;
    if (wid >= NSEG1 + NSEG2) return;

    int row0, col0;
    uint32_t *seg, *hdr;
    if (wid < NSEG1) {
        int rb = wid / S1_CH, ch = wid % S1_CH;
        row0 = rb * RB;          col0 = ch * C;
        seg = seg1 + (size_t)wid * SEG_U32;  hdr = hdr1 + wid;
    } else {
        int s  = wid - NSEG1;
        int rb = s / S2_CH, ch = s % S2_CH;
        row0 = N_HID + rb * RB;  col0 = ch * C;
        seg = seg2 + (size_t)s * SEG_U32;    hdr = hdr2 + s;
    }

    int n = 0;
    if (lane < RB) {
        const int* mrow = mat + (size_t)(row0 + lane) * SRC_DIM + col0;
        uint8_t* sb = (uint8_t*)seg;
        for (int c = 0; c < C; c++) {
            int code = mrow[c];
            if (code != 0) {
                uint8_t slot = (uint8_t)((code - 1) * C + c);
                if (n < 2) {
                    sb[2 * lane + n] = slot;               // plane-0 u16
                } else {
                    int j  = n - 2;                        // overflow index
                    int pl = j >> 1;                       // 0-based overflow plane
                    sb[(size_t)(8 + 9 * pl + 1 + (lane >> 1)) * 4
                       + (lane & 1) * 2 + (j & 1)] = slot;
                }
                n++;
            }
        }
    }
    int m = n;
    #pragma unroll
    for (int d = 1; d < 64; d <<= 1) m = max(m, __shfl_xor(m, d));
    uint32_t Wv = (m <= 2) ? 1u : 1u + (uint32_t)((m - 1) >> 1);

    for (uint32_t p = 1; p < Wv; p++) {
        unsigned long long b = __ballot(n > (int)(2 * p));
        if (lane == 0) seg[8 + 9 * (p - 1)] = (uint32_t)(b & 0xFFFFu);
    }
    if (lane == 0) *hdr = Wv;
}

// ---------------------------------------------------------------------------
// k_xt: transpose x[8192][1024] -> x_t[1024][8192] (fp32), 64x64 LDS tiles.
// ---------------------------------------------------------------------------
__global__ __launch_bounds__(256) void k_xt(const float* __restrict__ x,
                                            float* __restrict__ x_t) {
    __shared__ float t[64][65];
    const int b0 = blockIdx.x * 64, c0 = blockIdx.y * 64;
    {
        int r  = threadIdx.x >> 4;
        int cq = (threadIdx.x & 15) * 4;
        #pragma unroll
        for (int k = 0; k < 4; k++) {
            int rr = r + 16 * k;
            float4 v = *(const float4*)&x[(size_t)(b0 + rr) * IN_DIM + c0 + cq];
            t[rr][cq + 0] = v.x; t[rr][cq + 1] = v.y;
            t[rr][cq + 2] = v.z; t[rr][cq + 3] = v.w;
        }
    }
    __syncthreads();
    {
        int bq  = (threadIdx.x & 15) * 4;
        int cc0 = threadIdx.x >> 4;
        #pragma unroll
        for (int k = 0; k < 4; k++) {
            int cc = cc0 + 16 * k;
            float4 v;
            v.x = t[bq + 0][cc]; v.y = t[bq + 1][cc];
            v.z = t[bq + 2][cc]; v.w = t[bq + 3][cc];
            *(float4*)&x_t[(size_t)(c0 + cc) * BATCH + b0 + bq] = v;
        }
    }
}

typedef float v2f __attribute__((ext_vector_type(2)));

// pack two floats as bf16 pair: low16 = first, high16 = second
__device__ __forceinline__ uint32_t pack2(float a, float b) {
    __hip_bfloat162 h = __float22bfloat162_rn(make_float2(a, b));
    union { __hip_bfloat162 h2; uint32_t u; } u;
    u.h2 = h;
    return u.u;
}

__device__ __forceinline__ float rcp_f(float x) { return __builtin_amdgcn_rcpf(x); }

// write 4 activation slots for column c, 4 batches per lane (v pre-scaled by w).
// Trans budget/elem: 1 v_exp + 2 v_rcp.
// sigmoid = rcp(1+E), tanh = 2*rcp(1+E^2)-1  with E = exp(-v)  (robust at inf).
__device__ __forceinline__ void write_acts4(uint32_t* As, int c, int lane, float4 v) {
    *(uint2*)&As[(size_t)(0 * C + c) * 128 + 2 * lane] =
        make_uint2(pack2(v.x, v.y), pack2(v.z, v.w));
    *(uint2*)&As[(size_t)(1 * C + c) * 128 + 2 * lane] =
        make_uint2(pack2(fmaxf(v.x, 0.0f), fmaxf(v.y, 0.0f)),
                   pack2(fmaxf(v.z, 0.0f), fmaxf(v.w, 0.0f)));
    float ex = __expf(-v.x), ey = __expf(-v.y);
    float ez = __expf(-v.z), ew = __expf(-v.w);
    float tx = fmaf(2.0f, rcp_f(fmaf(ex, ex, 1.0f)), -1.0f);
    float ty = fmaf(2.0f, rcp_f(fmaf(ey, ey, 1.0f)), -1.0f);
    float tz = fmaf(2.0f, rcp_f(fmaf(ez, ez, 1.0f)), -1.0f);
    float tw = fmaf(2.0f, rcp_f(fmaf(ew, ew, 1.0f)), -1.0f);
    *(uint2*)&As[(size_t)(2 * C + c) * 128 + 2 * lane] =
        make_uint2(pack2(tx, ty), pack2(tz, tw));
    float sx = rcp_f(1.0f + ex), sy = rcp_f(1.0f + ey);
    float sz = rcp_f(1.0f + ez), sw = rcp_f(1.0f + ew);
    *(uint2*)&As[(size_t)(3 * C + c) * 128 + 2 * lane] =
        make_uint2(pack2(sx, sy), pack2(sz, sw));
}

// one slot: ds_read_b64 -> 2 bf16-pairs -> 2 v_pk_add_f32 (4 batches/lane).
// S is an SGPR value (scalarized record) -> v_lshl_add with SGPR src.
#define SLOT_ACC(AB, R, S)                                                     \
    {                                                                          \
        uint2 q_ = *(const uint2*)&(AB)[(size_t)(S) * 128 + 2 * lane];         \
        v2f ua_, ub_;                                                          \
        ua_.x = __uint_as_float(q_.x << 16);                                   \
        ua_.y = __uint_as_float(q_.x & 0xFFFF0000u);                           \
        ub_.x = __uint_as_float(q_.y << 16);                                   \
        ub_.y = __uint_as_float(q_.y & 0xFFFF0000u);                           \
        accA[R] += ua_;                                                        \
        accB[R] += ub_;                                                        \
    }

// All segment words are wave-uniform: readfirstlane -> SALU control flow
// (s_cmp/s_cbranch), SALU extracts (dual-issue vs VALU), no exec-mask churn.
// Slot words still load INSIDE guards (R4 lesson: no long-lived arrays).
#define EDGE_PLANES(AB, SEGBASE, WVAL)                                         \
    {                                                                          \
        const uint32_t* sp_ = (SEGBASE);                                       \
        uint4 pq0_ = *(const uint4*)sp_;                                       \
        uint4 pq1_ = *(const uint4*)(sp_ + 4);                                 \
        uint32_t g0_ = RFL(pq0_.x), g1_ = RFL(pq0_.y);                         \
        uint32_t g2_ = RFL(pq0_.z), g3_ = RFL(pq0_.w);                         \
        uint32_t g4_ = RFL(pq1_.x), g5_ = RFL(pq1_.y);                         \
        uint32_t g6_ = RFL(pq1_.z), g7_ = RFL(pq1_.w);                         \
        SLOT_ACC(AB,  0, g0_ & 255u)  SLOT_ACC(AB,  0, (g0_ >> 8) & 255u)      \
        SLOT_ACC(AB,  1, (g0_ >> 16) & 255u)  SLOT_ACC(AB,  1, g0_ >> 24)     \
        SLOT_ACC(AB,  2, g1_ & 255u)  SLOT_ACC(AB,  2, (g1_ >> 8) & 255u)      \
        SLOT_ACC(AB,  3, (g1_ >> 16) & 255u)  SLOT_ACC(AB,  3, g1_ >> 24)     \
        SLOT_ACC(AB,  4, g2_ & 255u)  SLOT_ACC(AB,  4, (g2_ >> 8) & 255u)      \
        SLOT_ACC(AB,  5, (g2_ >> 16) & 255u)  SLOT_ACC(AB,  5, g2_ >> 24)     \
        SLOT_ACC(AB,  6, g3_ & 255u)  SLOT_ACC(AB,  6, (g3_ >> 8) & 255u)      \
        SLOT_ACC(AB,  7, (g3_ >> 16) & 255u)  SLOT_ACC(AB,  7, g3_ >> 24)     \
        SLOT_ACC(AB,  8, g4_ & 255u)  SLOT_ACC(AB,  8, (g4_ >> 8) & 255u)      \
        SLOT_ACC(AB,  9, (g4_ >> 16) & 255u)  SLOT_ACC(AB,  9, g4_ >> 24)     \
        SLOT_ACC(AB, 10, g5_ & 255u)  SLOT_ACC(AB, 10, (g5_ >> 8) & 255u)      \
        SLOT_ACC(AB, 11, (g5_ >> 16) & 255u)  SLOT_ACC(AB, 11, g5_ >> 24)     \
        SLOT_ACC(AB, 12, g6_ & 255u)  SLOT_ACC(AB, 12, (g6_ >> 8) & 255u)      \
        SLOT_ACC(AB, 13, (g6_ >> 16) & 255u)  SLOT_ACC(AB, 13, g6_ >> 24)     \
        SLOT_ACC(AB, 14, g7_ & 255u)  SLOT_ACC(AB, 14, (g7_ >> 8) & 255u)      \
        SLOT_ACC(AB, 15, (g7_ >> 16) & 255u)  SLOT_ACC(AB, 15, g7_ >> 24)     \
        _Pragma("unroll 1")                                                    \
        for (uint32_t p = 1; p < (WVAL); p++) {                                \
            const uint32_t* pp_ = sp_ + 8 + 9 * (p - 1);                       \
            uint32_t mask = RFL(pp_[0]);                                       \
            _Pragma("unroll")                                                  \
            for (int r = 0; r < RB; r++) {                                     \
                if (mask & (1u << r)) {                                        \
                    uint32_t h_ = RFL(pp_[1 + (r >> 1)]);                      \
                    uint32_t u_ = (r & 1) ? (h_ >> 16) : h_;                   \
                    SLOT_ACC(AB, r, u_ & 255u)                                 \
                    SLOT_ACC(AB, r, (u_ >> 8) & 255u)                          \
                }                                                              \
            }                                                                  \
        }                                                                      \
    }

// ---------------------------------------------------------------------------
// Stage 1: 16 waves x 16 rows = 256 rows; 256 batches per block.
// Grid (32 tiles, 8 row splits) = 256 blocks. LDS 2 x 64.5 KB (dbuf),
// ONE barrier per chunk; acts(ch+1) writes overlap edge(ch) reads.
// ---------------------------------------------------------------------------
__global__ __launch_bounds__(1024, 4) void k_hid(const float* __restrict__ x_t,
                                                 const float* __restrict__ wp,
                                                 const uint32_t* __restrict__ seg1,
                                                 const uint32_t* __restrict__ hdr1,
                                                 __hip_bfloat16* __restrict__ hidden_t) {
    __shared__ uint32_t As[2 * ABUF_U32];       // 129 KB

    const float w  = wp[0];
    const int tile = blockIdx.x;                // 0..31
    const int lane = threadIdx.x & 63;
    const int wv   = __builtin_amdgcn_readfirstlane(threadIdx.x >> 6); // 0..15
    const int rb   = blockIdx.y * 16 + wv;      // row-block 0..127
    const int b0   = tile * BT;

    if (threadIdx.x < 128) {                    // both zero pages
        As[ZSLOT * 128 + threadIdx.x] = 0u;
        As[ABUF_U32 + ZSLOT * 128 + threadIdx.x] = 0u;
    }

    v2f accA[RB], accB[RB];
    #pragma unroll
    for (int r = 0; r < RB; r++) {
        accA[r] = (v2f)0.0f;
        accB[r] = (v2f)0.0f;
    }

    // prologue: acts(0) into buf0; prefetch v for chunk 1
    float4 v[2];
    #pragma unroll
    for (int j = 0; j < 2; j++) {
        int gcol = wv * 2 + j;
        const float2* xp = (const float2*)&x_t[(size_t)gcol * BATCH + b0];
        float2 u0 = xp[lane], u1 = xp[64 + lane];
        v[j] = make_float4(w * u0.x, w * u0.y, w * u1.x, w * u1.y);
    }
    write_acts4(As, wv * 2 + 0, lane, v[0]);
    write_acts4(As, wv * 2 + 1, lane, v[1]);
    #pragma unroll
    for (int j = 0; j < 2; j++) {
        int gcol = C + wv * 2 + j;
        const float2* xp = (const float2*)&x_t[(size_t)gcol * BATCH + b0];
        float2 u0 = xp[lane], u1 = xp[64 + lane];
        v[j] = make_float4(w * u0.x, w * u0.y, w * u1.x, w * u1.y);
    }
    __syncthreads();

    #pragma unroll 1
    for (int ch = 0; ch < S1_CH; ch++) {
        uint32_t* cur = As + (size_t)(ch & 1) * ABUF_U32;
        uint32_t* nxt = As + (size_t)((ch + 1) & 1) * ABUF_U32;
        if (ch + 1 < S1_CH) {
            write_acts4(nxt, wv * 2 + 0, lane, v[0]);
            write_acts4(nxt, wv * 2 + 1, lane, v[1]);
            if (ch + 2 < S1_CH) {
                #pragma unroll
                for (int j = 0; j < 2; j++) {
                    int gcol = (ch + 2) * C + wv * 2 + j;
                    const float2* xp = (const float2*)&x_t[(size_t)gcol * BATCH + b0];
                    float2 u0 = xp[lane], u1 = xp[64 + lane];
                    v[j] = make_float4(w * u0.x, w * u0.y, w * u1.x, w * u1.y);
                }
            }
        }
        int sidx = rb * S1_CH + ch;
        uint32_t W = RFL(hdr1[sidx]);
        EDGE_PLANES(cur, seg1 + (size_t)sidx * SEG_U32, W)
        __syncthreads();                        // acts(ch+1) ready; edge(ch) drained
    }

    const int row0 = rb * RB;
    #pragma unroll
    for (int r = 0; r < RB; r++) {
        *(uint32_t*)&hidden_t[(size_t)(row0 + r) * BATCH + b0 + 2 * lane] =
            pack2(accA[r].x, accA[r].y);
        *(uint32_t*)&hidden_t[(size_t)(row0 + r) * BATCH + b0 + 128 + 2 * lane] =
            pack2(accB[r].x, accB[r].y);
    }
}

// source loader for stage 2 (x_t fp32 or hidden_t bf16), pre-scaled by w
__device__ __forceinline__ float4 load_src4(const float* __restrict__ x_t,
                                            const __hip_bfloat16* __restrict__ hidden_t,
                                            int gcol, int b0, int lane, float w) {
    if (gcol < IN_DIM) {
        const float2* xp = (const float2*)&x_t[(size_t)gcol * BATCH + b0];
        float2 u0 = xp[lane], u1 = xp[64 + lane];
        return make_float4(w * u0.x, w * u0.y, w * u1.x, w * u1.y);
    } else {
        const uint16_t* hp = (const uint16_t*)&hidden_t[(size_t)(gcol - IN_DIM) * BATCH + b0];
        uint32_t q0 = *(const uint32_t*)&hp[2 * lane];
        uint32_t q1 = *(const uint32_t*)&hp[128 + 2 * lane];
        return make_float4(w * __uint_as_float(q0 << 16),
                           w * __uint_as_float(q0 & 0xFFFF0000u),
                           w * __uint_as_float(q1 << 16),
                           w * __uint_as_float(q1 & 0xFFFF0000u));
    }
}

// ---------------------------------------------------------------------------
// Stage 2: 16 waves x 16 rows = ALL 256 out rows; 256 batches per block.
// Grid (32 tiles, 8 chunk groups of 12) = 256 blocks. Dbuf as in k_hid.
// ---------------------------------------------------------------------------
__global__ __launch_bounds__(1024, 4) void k_out(const float* __restrict__ x_t,
                                                 const __hip_bfloat16* __restrict__ hidden_t,
                                                 const float* __restrict__ wp,
                                                 const uint32_t* __restrict__ seg2,
                                                 const uint32_t* __restrict__ hdr2,
                                                 float* __restrict__ partials) {
    __shared__ uint32_t As[2 * ABUF_U32];

    const float w  = wp[0];
    const int tile = blockIdx.x;                // 0..31
    const int cg   = blockIdx.y;                // 0..7
    const int lane = threadIdx.x & 63;
    const int wv   = __builtin_amdgcn_readfirstlane(threadIdx.x >> 6); // 0..15
    const int b0   = tile * BT;

    if (threadIdx.x < 128) {
        As[ZSLOT * 128 + threadIdx.x] = 0u;
        As[ABUF_U32 + ZSLOT * 128 + threadIdx.x] = 0u;
    }

    v2f accA[RB], accB[RB];
    #pragma unroll
    for (int r = 0; r < RB; r++) {
        accA[r] = (v2f)0.0f;
        accB[r] = (v2f)0.0f;
    }

    float4 v[2];
    #pragma unroll
    for (int j = 0; j < 2; j++)
        v[j] = load_src4(x_t, hidden_t, (cg * 12) * C + wv * 2 + j, b0, lane, w);
    write_acts4(As, wv * 2 + 0, lane, v[0]);
    write_acts4(As, wv * 2 + 1, lane, v[1]);
    #pragma unroll
    for (int j = 0; j < 2; j++)
        v[j] = load_src4(x_t, hidden_t, (cg * 12 + 1) * C + wv * 2 + j, b0, lane, w);
    __syncthreads();

    #pragma unroll 1
    for (int cj = 0; cj < 12; cj++) {
        int ch = cg * 12 + cj;
        uint32_t* cur = As + (size_t)(cj & 1) * ABUF_U32;
        uint32_t* nxt = As + (size_t)((cj + 1) & 1) * ABUF_U32;
        if (cj + 1 < 12) {
            write_acts4(nxt, wv * 2 + 0, lane, v[0]);
            write_acts4(nxt, wv * 2 + 1, lane, v[1]);
            if (cj + 2 < 12) {
                #pragma unroll
                for (int j = 0; j < 2; j++)
                    v[j] = load_src4(x_t, hidden_t, (ch + 2) * C + wv * 2 + j, b0, lane, w);
            }
        }
        int sidx = wv * S2_CH + ch;              // wv = row-block 0..15
        uint32_t W = RFL(hdr2[sidx]);
        EDGE_PLANES(cur, seg2 + (size_t)sidx * SEG_U32, W)
        __syncthreads();
    }

    #pragma unroll
    for (int r = 0; r < RB; r++) {
        size_t base = ((size_t)cg * OUT_DIM + wv * RB + r) * BATCH + b0;
        *(v2f*)&partials[base + 2 * lane]       = accA[r];
        *(v2f*)&partials[base + 128 + 2 * lane] = accB[r];
    }
}

// ---------------------------------------------------------------------------
// k_sum: reduce 8 partial planes + transpose [r][b] -> out[b][r] (float4).
// ---------------------------------------------------------------------------
__global__ __launch_bounds__(256) void k_sum(const float* __restrict__ partials,
                                             float* __restrict__ out) {
    __shared__ float t[16][65];
    const int b0 = blockIdx.x * 64, r0 = blockIdx.y * 16;
    const int lane = threadIdx.x & 63;
    const int g4   = threadIdx.x >> 6;

    #pragma unroll
    for (int k = 0; k < 4; k++) {
        int rr = g4 * 4 + k;
        float s = 0.0f;
        #pragma unroll
        for (int cg = 0; cg < 8; cg++)
            s += partials[((size_t)cg * OUT_DIM + r0 + rr) * BATCH + b0 + lane];
        t[rr][lane] = s;
    }
    __syncthreads();
    int bb = threadIdx.x >> 2, rq = threadIdx.x & 3;
    float4 v;
    v.x = t[rq * 4 + 0][bb];
    v.y = t[rq * 4 + 1][bb];
    v.z = t[rq * 4 + 2][bb];
    v.w = t[rq * 4 + 3][bb];
    *(float4*)&out[(size_t)(b0 + bb) * OUT_DIM + r0 + rq * 4] = v;
}

// ---------------------------------------------------------------------------
extern "C" void kernel_launch(void* const* d_in, const int* in_sizes, int n_in,
                              void* d_out, int out_size, void* d_ws, size_t ws_size,
                              hipStream_t stream) {
    const float* x   = (const float*)d_in[0];
    const float* w   = (const float*)d_in[1];
    const int*   mat = (const int*)d_in[2];
    float* out = (float*)d_out;

    uint8_t* ws = (uint8_t*)d_ws;
    size_t off = 0;
    __hip_bfloat16* hidden_t = (__hip_bfloat16*)(ws + off); off += (size_t)BATCH * N_HID * 2;  // 33.6 MB
    float* x_t = (float*)(ws + off);        off += (size_t)IN_DIM * BATCH * 4;                 // 33.6 MB
    uint32_t* seg1 = (uint32_t*)(ws + off); off += (size_t)NSEG1 * SEG_U32 * 4;                //  2.62 MB
    uint32_t* seg2 = (uint32_t*)(ws + off); off += (size_t)NSEG2 * SEG_U32 * 4;                //  0.98 MB
    uint32_t* hdr1 = (uint32_t*)(ws + off); off += (size_t)NSEG1 * 4;
    uint32_t* hdr2 = (uint32_t*)(ws + off); off += (size_t)NSEG2 * 4;
    float* partials = (float*)(ws + off);   off += (size_t)8 * OUT_DIM * BATCH * 4;            // 67.1 MB
    (void)ws_size; (void)in_sizes; (void)n_in; (void)out_size;

    hipMemsetAsync(seg1, 0x80, (size_t)(NSEG1 + NSEG2) * SEG_U32 * 4, stream);

    {
        int nseg = NSEG1 + NSEG2;                   // 5632 waves
        k_prep<<<(nseg + 3) / 4, 256, 0, stream>>>(mat, seg1, seg2, hdr1, hdr2);
    }
    {
        dim3 g(BATCH / 64, IN_DIM / 64);            // 128 x 16
        k_xt<<<g, 256, 0, stream>>>(x, x_t);
    }
    {
        dim3 g(BATCH / BT, 8);                      // 32 x 8 = 256 blocks
        k_hid<<<g, 1024, 0, stream>>>(x_t, w, seg1, hdr1, hidden_t);
    }
    {
        dim3 g(BATCH / BT, 8);                      // 32 x 8 = 256 blocks
        k_out<<<g, 1024, 0, stream>>>(x_t, hidden_t, w, seg2, hdr2, partials);
    }
    {
        dim3 g(BATCH / 64, OUT_DIM / 16);           // 2048 blocks
        k_sum<<<g, 256, 0, stream>>>(partials, out);
    }
}

// Round 7
// 319.798 us; speedup vs baseline: 48.0934x; 1.1053x over previous
//
#include <hip/hip_runtime.h>
#include <hip/hip_bf16.h>
#include <stdint.h>

// Problem constants
#define BATCH   8192
#define IN_DIM  1024
#define N_HID   2048
#define OUT_DIM 256
#define SRC_DIM 3072

// Tiling
#define C     32                   // source columns per chunk
#define RB    16                   // rows per row-block (= rows per wave)
#define BT    256                  // batch per block (4/lane: 2l,2l+1,128+2l,128+2l+1)
#define S1_CH (IN_DIM / C)         // 32
#define S1_RB (N_HID / RB)         // 128
#define S2_CH (SRC_DIM / C)        // 96
#define S2_RB (OUT_DIM / RB)       // 16
#define NSEG1 (S1_RB * S1_CH)      // 4096
#define NSEG2 (S2_RB * S2_CH)      // 1536
#define ZSLOT 128                  // A-tile zero page (pad byte 0x80)
#define SEG_U32 160                // segment stride (640 B; max 15 overflow planes)
#define ABUF_U32 ((4 * C + 1) * 128)  // 16512 u32 = 64.5 KB per A-tile buffer

// Segment format v5 (granule-2 overflow; plane-0 identical to proven v3):
//   u32[0..7]   plane-0: row r -> u16 at byte 2r (2 slot bytes, pad 0x80)
//   overflow planes p=1..15 at u32 8+9(p-1), stride 9:
//     [0]    = 16-bit row mask (rows with n > 2p)
//     [1..8] = u16 per row: 2 slot bytes for overflow idx 2(p-1), 2(p-1)+1
// R1: vector gating ~70 VALU/slot -> plane-0 unconditional, pads hit zero page.
// R2: BT=256 halved per-elem VALU; 1 block/CU exposes skew.
// R3: dbuf + 1 barrier/chunk recovered skew (206->157).
// R4 (9297us): long-lived preload arrays -> acc spill to SCRATCH.
// R5/R6: granule-2 + pk_add small win; RFL neutral (already scalar).
// R7 THEORY: VGPR_Count=52 < 64 acc regs => accs live in AGPRs (scheduler
// batches ~32 ds_reads -> ~64 temp VGPRs -> allocator spills accs to AGPR;
// each acc use = accvgpr_read/write RMW ~6 VALU instead of 1 pk_add ->
// explains measured ~890 instr/chunk-wave vs ~420 modeled, chronic since R0).
// FIX: sched_barrier(0) every 8 slots caps temp pressure -> accs back in
// arch VGPRs. VERIFY: VGPR_Count should jump to ~96+.

#define RFL(x) __builtin_amdgcn_readfirstlane((uint32_t)(x))
#define SBAR __builtin_amdgcn_sched_barrier(0);

// ---------------------------------------------------------------------------
__global__ void k_prep(const int* __restrict__ mat,
                       uint32_t* __restrict__ seg1, uint32_t* __restrict__ seg2,
                       uint32_t* __restrict__ hdr1, uint32_t* __restrict__ hdr2) {
    int wid  = (blockIdx.x * blockDim.x + threadIdx.x) >> 6;
    int lane = threadIdx.x & 63;
    if (wid >= NSEG1 + NSEG2) return;

    int row0, col0;
    uint32_t *seg, *hdr;
    if (wid < NSEG1) {
        int rb = wid / S1_CH, ch = wid % S1_CH;
        row0 = rb * RB;          col0 = ch * C;
        seg = seg1 + (size_t)wid * SEG_U32;  hdr = hdr1 + wid;
    } else {
        int s  = wid - NSEG1;
        int rb = s / S2_CH, ch = s % S2_CH;
        row0 = N_HID + rb * RB;  col0 = ch * C;
        seg = seg2 + (size_t)s * SEG_U32;    hdr = hdr2 + s;
    }

    int n = 0;
    if (lane < RB) {
        const int* mrow = mat + (size_t)(row0 + lane) * SRC_DIM + col0;
        uint8_t* sb = (uint8_t*)seg;
        for (int c = 0; c < C; c++) {
            int code = mrow[c];
            if (code != 0) {
                uint8_t slot = (uint8_t)((code - 1) * C + c);
                if (n < 2) {
                    sb[2 * lane + n] = slot;               // plane-0 u16
                } else {
                    int j  = n - 2;                        // overflow index
                    int pl = j >> 1;                       // 0-based overflow plane
                    sb[(size_t)(8 + 9 * pl + 1 + (lane >> 1)) * 4
                       + (lane & 1) * 2 + (j & 1)] = slot;
                }
                n++;
            }
        }
    }
    int m = n;
    #pragma unroll
    for (int d = 1; d < 64; d <<= 1) m = max(m, __shfl_xor(m, d));
    uint32_t Wv = (m <= 2) ? 1u : 1u + (uint32_t)((m - 1) >> 1);

    for (uint32_t p = 1; p < Wv; p++) {
        unsigned long long b = __ballot(n > (int)(2 * p));
        if (lane == 0) seg[8 + 9 * (p - 1)] = (uint32_t)(b & 0xFFFFu);
    }
    if (lane == 0) *hdr = Wv;
}

// ---------------------------------------------------------------------------
// k_xt: transpose x[8192][1024] -> x_t[1024][8192] (fp32), 64x64 LDS tiles.
// ---------------------------------------------------------------------------
__global__ __launch_bounds__(256) void k_xt(const float* __restrict__ x,
                                            float* __restrict__ x_t) {
    __shared__ float t[64][65];
    const int b0 = blockIdx.x * 64, c0 = blockIdx.y * 64;
    {
        int r  = threadIdx.x >> 4;
        int cq = (threadIdx.x & 15) * 4;
        #pragma unroll
        for (int k = 0; k < 4; k++) {
            int rr = r + 16 * k;
            float4 v = *(const float4*)&x[(size_t)(b0 + rr) * IN_DIM + c0 + cq];
            t[rr][cq + 0] = v.x; t[rr][cq + 1] = v.y;
            t[rr][cq + 2] = v.z; t[rr][cq + 3] = v.w;
        }
    }
    __syncthreads();
    {
        int bq  = (threadIdx.x & 15) * 4;
        int cc0 = threadIdx.x >> 4;
        #pragma unroll
        for (int k = 0; k < 4; k++) {
            int cc = cc0 + 16 * k;
            float4 v;
            v.x = t[bq + 0][cc]; v.y = t[bq + 1][cc];
            v.z = t[bq + 2][cc]; v.w = t[bq + 3][cc];
            *(float4*)&x_t[(size_t)(c0 + cc) * BATCH + b0 + bq] = v;
        }
    }
}

typedef float v2f __attribute__((ext_vector_type(2)));

// pack two floats as bf16 pair: low16 = first, high16 = second
__device__ __forceinline__ uint32_t pack2(float a, float b) {
    __hip_bfloat162 h = __float22bfloat162_rn(make_float2(a, b));
    union { __hip_bfloat162 h2; uint32_t u; } u;
    u.h2 = h;
    return u.u;
}

__device__ __forceinline__ float rcp_f(float x) { return __builtin_amdgcn_rcpf(x); }

// write 4 activation slots for column c, 4 batches per lane (v pre-scaled by w).
// Trans budget/elem: 1 v_exp + 2 v_rcp.
// sigmoid = rcp(1+E), tanh = 2*rcp(1+E^2)-1  with E = exp(-v)  (robust at inf).
__device__ __forceinline__ void write_acts4(uint32_t* As, int c, int lane, float4 v) {
    *(uint2*)&As[(size_t)(0 * C + c) * 128 + 2 * lane] =
        make_uint2(pack2(v.x, v.y), pack2(v.z, v.w));
    *(uint2*)&As[(size_t)(1 * C + c) * 128 + 2 * lane] =
        make_uint2(pack2(fmaxf(v.x, 0.0f), fmaxf(v.y, 0.0f)),
                   pack2(fmaxf(v.z, 0.0f), fmaxf(v.w, 0.0f)));
    float ex = __expf(-v.x), ey = __expf(-v.y);
    float ez = __expf(-v.z), ew = __expf(-v.w);
    float tx = fmaf(2.0f, rcp_f(fmaf(ex, ex, 1.0f)), -1.0f);
    float ty = fmaf(2.0f, rcp_f(fmaf(ey, ey, 1.0f)), -1.0f);
    float tz = fmaf(2.0f, rcp_f(fmaf(ez, ez, 1.0f)), -1.0f);
    float tw = fmaf(2.0f, rcp_f(fmaf(ew, ew, 1.0f)), -1.0f);
    *(uint2*)&As[(size_t)(2 * C + c) * 128 + 2 * lane] =
        make_uint2(pack2(tx, ty), pack2(tz, tw));
    float sx = rcp_f(1.0f + ex), sy = rcp_f(1.0f + ey);
    float sz = rcp_f(1.0f + ez), sw = rcp_f(1.0f + ew);
    *(uint2*)&As[(size_t)(3 * C + c) * 128 + 2 * lane] =
        make_uint2(pack2(sx, sy), pack2(sz, sw));
}

// one slot: ds_read_b64 -> 2 bf16-pairs -> 2 v_pk_add_f32 (4 batches/lane).
#define SLOT_ACC(AB, R, S)                                                     \
    {                                                                          \
        uint2 q_ = *(const uint2*)&(AB)[(size_t)(S) * 128 + 2 * lane];         \
        v2f ua_, ub_;                                                          \
        ua_.x = __uint_as_float(q_.x << 16);                                   \
        ua_.y = __uint_as_float(q_.x & 0xFFFF0000u);                           \
        ub_.x = __uint_as_float(q_.y << 16);                                   \
        ub_.y = __uint_as_float(q_.y & 0xFFFF0000u);                           \
        accA[R] += ua_;                                                        \
        accB[R] += ub_;                                                        \
    }

// Plane-0 unconditional; sched_barrier(0) every 2 g-words (8 slots) caps the
// scheduler's ds_read batching (~16 live temps instead of ~64) so the 64 acc
// regs stay in arch VGPRs (R7 theory). Overflow rows: scalar-gated, loaded
// inside the guard (R4 lesson).
#define EDGE_PLANES(AB, SEGBASE, WVAL)                                         \
    {                                                                          \
        const uint32_t* sp_ = (SEGBASE);                                       \
        uint32_t g0_ = RFL(sp_[0]), g1_ = RFL(sp_[1]);                         \
        SLOT_ACC(AB, 0, g0_ & 255u)  SLOT_ACC(AB, 0, (g0_ >> 8) & 255u)        \
        SLOT_ACC(AB, 1, (g0_ >> 16) & 255u)  SLOT_ACC(AB, 1, g0_ >> 24)        \
        SLOT_ACC(AB, 2, g1_ & 255u)  SLOT_ACC(AB, 2, (g1_ >> 8) & 255u)        \
        SLOT_ACC(AB, 3, (g1_ >> 16) & 255u)  SLOT_ACC(AB, 3, g1_ >> 24)        \
        SBAR                                                                   \
        uint32_t g2_ = RFL(sp_[2]), g3_ = RFL(sp_[3]);                         \
        SLOT_ACC(AB, 4, g2_ & 255u)  SLOT_ACC(AB, 4, (g2_ >> 8) & 255u)        \
        SLOT_ACC(AB, 5, (g2_ >> 16) & 255u)  SLOT_ACC(AB, 5, g2_ >> 24)        \
        SLOT_ACC(AB, 6, g3_ & 255u)  SLOT_ACC(AB, 6, (g3_ >> 8) & 255u)        \
        SLOT_ACC(AB, 7, (g3_ >> 16) & 255u)  SLOT_ACC(AB, 7, g3_ >> 24)        \
        SBAR                                                                   \
        uint32_t g4_ = RFL(sp_[4]), g5_ = RFL(sp_[5]);                         \
        SLOT_ACC(AB, 8, g4_ & 255u)  SLOT_ACC(AB, 8, (g4_ >> 8) & 255u)        \
        SLOT_ACC(AB, 9, (g4_ >> 16) & 255u)  SLOT_ACC(AB, 9, g4_ >> 24)        \
        SLOT_ACC(AB, 10, g5_ & 255u)  SLOT_ACC(AB, 10, (g5_ >> 8) & 255u)      \
        SLOT_ACC(AB, 11, (g5_ >> 16) & 255u)  SLOT_ACC(AB, 11, g5_ >> 24)      \
        SBAR                                                                   \
        uint32_t g6_ = RFL(sp_[6]), g7_ = RFL(sp_[7]);                         \
        SLOT_ACC(AB, 12, g6_ & 255u)  SLOT_ACC(AB, 12, (g6_ >> 8) & 255u)      \
        SLOT_ACC(AB, 13, (g6_ >> 16) & 255u)  SLOT_ACC(AB, 13, g6_ >> 24)      \
        SLOT_ACC(AB, 14, g7_ & 255u)  SLOT_ACC(AB, 14, (g7_ >> 8) & 255u)      \
        SLOT_ACC(AB, 15, (g7_ >> 16) & 255u)  SLOT_ACC(AB, 15, g7_ >> 24)      \
        SBAR                                                                   \
        _Pragma("unroll 1")                                                    \
        for (uint32_t p = 1; p < (WVAL); p++) {                                \
            const uint32_t* pp_ = sp_ + 8 + 9 * (p - 1);                       \
            uint32_t mask = RFL(pp_[0]);                                       \
            _Pragma("unroll")                                                  \
            for (int r = 0; r < RB; r++) {                                     \
                if (mask & (1u << r)) {                                        \
                    uint32_t h_ = RFL(pp_[1 + (r >> 1)]);                      \
                    uint32_t u_ = (r & 1) ? (h_ >> 16) : h_;                   \
                    SLOT_ACC(AB, r, u_ & 255u)                                 \
                    SLOT_ACC(AB, r, (u_ >> 8) & 255u)                          \
                }                                                              \
            }                                                                  \
        }                                                                      \
    }

// ---------------------------------------------------------------------------
// Stage 1: 16 waves x 16 rows = 256 rows; 256 batches per block.
// Grid (32 tiles, 8 row splits) = 256 blocks. LDS 2 x 64.5 KB (dbuf),
// ONE barrier per chunk; acts(ch+1) writes overlap edge(ch) reads.
// ---------------------------------------------------------------------------
__global__ __launch_bounds__(1024, 4) void k_hid(const float* __restrict__ x_t,
                                                 const float* __restrict__ wp,
                                                 const uint32_t* __restrict__ seg1,
                                                 const uint32_t* __restrict__ hdr1,
                                                 __hip_bfloat16* __restrict__ hidden_t) {
    __shared__ uint32_t As[2 * ABUF_U32];       // 129 KB

    const float w  = wp[0];
    const int tile = blockIdx.x;                // 0..31
    const int lane = threadIdx.x & 63;
    const int wv   = __builtin_amdgcn_readfirstlane(threadIdx.x >> 6); // 0..15
    const int rb   = blockIdx.y * 16 + wv;      // row-block 0..127
    const int b0   = tile * BT;

    if (threadIdx.x < 128) {                    // both zero pages
        As[ZSLOT * 128 + threadIdx.x] = 0u;
        As[ABUF_U32 + ZSLOT * 128 + threadIdx.x] = 0u;
    }

    v2f accA[RB], accB[RB];
    #pragma unroll
    for (int r = 0; r < RB; r++) {
        accA[r] = (v2f)0.0f;
        accB[r] = (v2f)0.0f;
    }

    // prologue: acts(0) into buf0; prefetch v for chunk 1
    float4 v[2];
    #pragma unroll
    for (int j = 0; j < 2; j++) {
        int gcol = wv * 2 + j;
        const float2* xp = (const float2*)&x_t[(size_t)gcol * BATCH + b0];
        float2 u0 = xp[lane], u1 = xp[64 + lane];
        v[j] = make_float4(w * u0.x, w * u0.y, w * u1.x, w * u1.y);
    }
    write_acts4(As, wv * 2 + 0, lane, v[0]);
    write_acts4(As, wv * 2 + 1, lane, v[1]);
    #pragma unroll
    for (int j = 0; j < 2; j++) {
        int gcol = C + wv * 2 + j;
        const float2* xp = (const float2*)&x_t[(size_t)gcol * BATCH + b0];
        float2 u0 = xp[lane], u1 = xp[64 + lane];
        v[j] = make_float4(w * u0.x, w * u0.y, w * u1.x, w * u1.y);
    }
    __syncthreads();

    #pragma unroll 1
    for (int ch = 0; ch < S1_CH; ch++) {
        uint32_t* cur = As + (size_t)(ch & 1) * ABUF_U32;
        uint32_t* nxt = As + (size_t)((ch + 1) & 1) * ABUF_U32;
        if (ch + 1 < S1_CH) {
            write_acts4(nxt, wv * 2 + 0, lane, v[0]);
            write_acts4(nxt, wv * 2 + 1, lane, v[1]);
            if (ch + 2 < S1_CH) {
                #pragma unroll
                for (int j = 0; j < 2; j++) {
                    int gcol = (ch + 2) * C + wv * 2 + j;
                    const float2* xp = (const float2*)&x_t[(size_t)gcol * BATCH + b0];
                    float2 u0 = xp[lane], u1 = xp[64 + lane];
                    v[j] = make_float4(w * u0.x, w * u0.y, w * u1.x, w * u1.y);
                }
            }
        }
        int sidx = rb * S1_CH + ch;
        uint32_t W = RFL(hdr1[sidx]);
        EDGE_PLANES(cur, seg1 + (size_t)sidx * SEG_U32, W)
        __syncthreads();                        // acts(ch+1) ready; edge(ch) drained
    }

    const int row0 = rb * RB;
    #pragma unroll
    for (int r = 0; r < RB; r++) {
        *(uint32_t*)&hidden_t[(size_t)(row0 + r) * BATCH + b0 + 2 * lane] =
            pack2(accA[r].x, accA[r].y);
        *(uint32_t*)&hidden_t[(size_t)(row0 + r) * BATCH + b0 + 128 + 2 * lane] =
            pack2(accB[r].x, accB[r].y);
    }
}

// source loader for stage 2 (x_t fp32 or hidden_t bf16), pre-scaled by w
__device__ __forceinline__ float4 load_src4(const float* __restrict__ x_t,
                                            const __hip_bfloat16* __restrict__ hidden_t,
                                            int gcol, int b0, int lane, float w) {
    if (gcol < IN_DIM) {
        const float2* xp = (const float2*)&x_t[(size_t)gcol * BATCH + b0];
        float2 u0 = xp[lane], u1 = xp[64 + lane];
        return make_float4(w * u0.x, w * u0.y, w * u1.x, w * u1.y);
    } else {
        const uint16_t* hp = (const uint16_t*)&hidden_t[(size_t)(gcol - IN_DIM) * BATCH + b0];
        uint32_t q0 = *(const uint32_t*)&hp[2 * lane];
        uint32_t q1 = *(const uint32_t*)&hp[128 + 2 * lane];
        return make_float4(w * __uint_as_float(q0 << 16),
                           w * __uint_as_float(q0 & 0xFFFF0000u),
                           w * __uint_as_float(q1 << 16),
                           w * __uint_as_float(q1 & 0xFFFF0000u));
    }
}

// ---------------------------------------------------------------------------
// Stage 2: 16 waves x 16 rows = ALL 256 out rows; 256 batches per block.
// Grid (32 tiles, 8 chunk groups of 12) = 256 blocks. Dbuf as in k_hid.
// Partials now bf16-packed u32 (2 batches/word): halves k_out epilogue and
// k_sum traffic (67 -> 33.5 MB).
// ---------------------------------------------------------------------------
__global__ __launch_bounds__(1024, 4) void k_out(const float* __restrict__ x_t,
                                                 const __hip_bfloat16* __restrict__ hidden_t,
                                                 const float* __restrict__ wp,
                                                 const uint32_t* __restrict__ seg2,
                                                 const uint32_t* __restrict__ hdr2,
                                                 uint32_t* __restrict__ partials) {
    __shared__ uint32_t As[2 * ABUF_U32];

    const float w  = wp[0];
    const int tile = blockIdx.x;                // 0..31
    const int cg   = blockIdx.y;                // 0..7
    const int lane = threadIdx.x & 63;
    const int wv   = __builtin_amdgcn_readfirstlane(threadIdx.x >> 6); // 0..15
    const int b0   = tile * BT;

    if (threadIdx.x < 128) {
        As[ZSLOT * 128 + threadIdx.x] = 0u;
        As[ABUF_U32 + ZSLOT * 128 + threadIdx.x] = 0u;
    }

    v2f accA[RB], accB[RB];
    #pragma unroll
    for (int r = 0; r < RB; r++) {
        accA[r] = (v2f)0.0f;
        accB[r] = (v2f)0.0f;
    }

    float4 v[2];
    #pragma unroll
    for (int j = 0; j < 2; j++)
        v[j] = load_src4(x_t, hidden_t, (cg * 12) * C + wv * 2 + j, b0, lane, w);
    write_acts4(As, wv * 2 + 0, lane, v[0]);
    write_acts4(As, wv * 2 + 1, lane, v[1]);
    #pragma unroll
    for (int j = 0; j < 2; j++)
        v[j] = load_src4(x_t, hidden_t, (cg * 12 + 1) * C + wv * 2 + j, b0, lane, w);
    __syncthreads();

    #pragma unroll 1
    for (int cj = 0; cj < 12; cj++) {
        int ch = cg * 12 + cj;
        uint32_t* cur = As + (size_t)(cj & 1) * ABUF_U32;
        uint32_t* nxt = As + (size_t)((cj + 1) & 1) * ABUF_U32;
        if (cj + 1 < 12) {
            write_acts4(nxt, wv * 2 + 0, lane, v[0]);
            write_acts4(nxt, wv * 2 + 1, lane, v[1]);
            if (cj + 2 < 12) {
                #pragma unroll
                for (int j = 0; j < 2; j++)
                    v[j] = load_src4(x_t, hidden_t, (ch + 2) * C + wv * 2 + j, b0, lane, w);
            }
        }
        int sidx = wv * S2_CH + ch;              // wv = row-block 0..15
        uint32_t W = RFL(hdr2[sidx]);
        EDGE_PLANES(cur, seg2 + (size_t)sidx * SEG_U32, W)
        __syncthreads();
    }

    #pragma unroll
    for (int r = 0; r < RB; r++) {
        size_t base = ((size_t)cg * OUT_DIM + wv * RB + r) * (BATCH / 2) + (b0 >> 1);
        partials[base + lane]      = pack2(accA[r].x, accA[r].y);
        partials[base + 64 + lane] = pack2(accB[r].x, accB[r].y);
    }
}

// ---------------------------------------------------------------------------
// k_sum: reduce 8 bf16-packed partial planes + transpose -> out[b][r].
// Block: 128 batches x 16 rows. Grid (64, 16).
// ---------------------------------------------------------------------------
__global__ __launch_bounds__(256) void k_sum(const uint32_t* __restrict__ partials,
                                             float* __restrict__ out) {
    __shared__ float t[16][130];
    const int b0 = blockIdx.x * 128, r0 = blockIdx.y * 16;
    const int lane = threadIdx.x & 63;
    const int g4   = threadIdx.x >> 6;          // 0..3

    #pragma unroll
    for (int k = 0; k < 4; k++) {
        int rr = g4 * 4 + k;
        float sx = 0.0f, sy = 0.0f;
        #pragma unroll
        for (int cg = 0; cg < 8; cg++) {
            uint32_t q = partials[((size_t)cg * OUT_DIM + r0 + rr) * (BATCH / 2)
                                  + (b0 >> 1) + lane];
            sx += __uint_as_float(q << 16);
            sy += __uint_as_float(q & 0xFFFF0000u);
        }
        t[rr][2 * lane]     = sx;
        t[rr][2 * lane + 1] = sy;
    }
    __syncthreads();
    #pragma unroll
    for (int k = 0; k < 2; k++) {
        int idx = threadIdx.x + 256 * k;        // 0..511
        int bb = idx >> 2, rq = idx & 3;
        float4 v;
        v.x = t[rq * 4 + 0][bb];
        v.y = t[rq * 4 + 1][bb];
        v.z = t[rq * 4 + 2][bb];
        v.w = t[rq * 4 + 3][bb];
        *(float4*)&out[(size_t)(b0 + bb) * OUT_DIM + r0 + rq * 4] = v;
    }
}

// ---------------------------------------------------------------------------
extern "C" void kernel_launch(void* const* d_in, const int* in_sizes, int n_in,
                              void* d_out, int out_size, void* d_ws, size_t ws_size,
                              hipStream_t stream) {
    const float* x   = (const float*)d_in[0];
    const float* w   = (const float*)d_in[1];
    const int*   mat = (const int*)d_in[2];
    float* out = (float*)d_out;

    uint8_t* ws = (uint8_t*)d_ws;
    size_t off = 0;
    __hip_bfloat16* hidden_t = (__hip_bfloat16*)(ws + off); off += (size_t)BATCH * N_HID * 2;  // 33.6 MB
    float* x_t = (float*)(ws + off);        off += (size_t)IN_DIM * BATCH * 4;                 // 33.6 MB
    uint32_t* seg1 = (uint32_t*)(ws + off); off += (size_t)NSEG1 * SEG_U32 * 4;                //  2.62 MB
    uint32_t* seg2 = (uint32_t*)(ws + off); off += (size_t)NSEG2 * SEG_U32 * 4;                //  0.98 MB
    uint32_t* hdr1 = (uint32_t*)(ws + off); off += (size_t)NSEG1 * 4;
    uint32_t* hdr2 = (uint32_t*)(ws + off); off += (size_t)NSEG2 * 4;
    uint32_t* partials = (uint32_t*)(ws + off); off += (size_t)8 * OUT_DIM * (BATCH / 2) * 4;  // 33.6 MB
    (void)ws_size; (void)in_sizes; (void)n_in; (void)out_size;

    hipMemsetAsync(seg1, 0x80, (size_t)(NSEG1 + NSEG2) * SEG_U32 * 4, stream);

    {
        int nseg = NSEG1 + NSEG2;                   // 5632 waves
        k_prep<<<(nseg + 3) / 4, 256, 0, stream>>>(mat, seg1, seg2, hdr1, hdr2);
    }
    {
        dim3 g(BATCH / 64, IN_DIM / 64);            // 128 x 16
        k_xt<<<g, 256, 0, stream>>>(x, x_t);
    }
    {
        dim3 g(BATCH / BT, 8);                      // 32 x 8 = 256 blocks
        k_hid<<<g, 1024, 0, stream>>>(x_t, w, seg1, hdr1, hidden_t);
    }
    {
        dim3 g(BATCH / BT, 8);                      // 32 x 8 = 256 blocks
        k_out<<<g, 1024, 0, stream>>>(x_t, hidden_t, w, seg2, hdr2, partials);
    }
    {
        dim3 g(BATCH / 128, OUT_DIM / 16);          // 64 x 16 = 1024 blocks
        k_sum<<<g, 256, 0, stream>>>(partials, out);
    }
}

// Round 8
// 315.026 us; speedup vs baseline: 48.8219x; 1.0151x over previous
//
#include <hip/hip_runtime.h>
#include <hip/hip_bf16.h>
#include <stdint.h>

// Problem constants
#define BATCH   8192
#define IN_DIM  1024
#define N_HID   2048
#define OUT_DIM 256
#define SRC_DIM 3072

// Tiling
#define C     32                   // source columns per chunk
#define RB    16                   // rows per row-block (= rows per wave)
#define BT    256                  // batch per block (4/lane)
#define S1_CH (IN_DIM / C)         // 32
#define S1_RB (N_HID / RB)         // 128
#define S2_CH (SRC_DIM / C)        // 96
#define S2_RB (OUT_DIM / RB)       // 16
#define NSEG1 (S1_RB * S1_CH)      // 4096
#define NSEG2 (S2_RB * S2_CH)      // 1536
#define ZSLOT 128                  // A-tile zero page (pad byte 0x80)
#define SEG_U32 160                // segment stride (640 B)
#define ABUF_U32 ((4 * C + 1) * 128)  // 16512 u32 = 64.5 KB A-tile (single buf)

// R1: vector gating ~70 VALU/slot -> plane-0 unconditional, pads hit zero page.
// R2: BT=256 halved per-elem VALU; 1 block/CU exposed skew (2 barriers).
// R3: dbuf + 1 barrier/chunk = 157 (stall 34%).
// R4 (9297us): long-lived arrays -> acc scratch spill. Load inside guards.
// R5-R7: granule-2/pk_add small wins; RFL + sched_barrier NEUTRAL; AGPR/
//   codegen-bloat theories falsified (VGPR stayed 52, no scratch).
// R8 THEORY: grid = 256 blocks = 1 block/CU since R2 (Occupancy 44%); the
// only high-issue datapoint is R0 (2 blocks/CU, VALUBusy 80%, wall/work
// 1.24 vs current 1.57). CHUNK-SPLIT is the only split with no acts tax:
// k_hid -> 2 chunk-groups x 16 chunks, single-buf A-tile (66KB x 2 = 132KB),
// 512 blocks = 2/CU, bf16 partial hidden planes summed in k_out's loads.
// VERIFY: Occupancy ~80, VGPR must stay <=64.

#define RFL(x) __builtin_amdgcn_readfirstlane((uint32_t)(x))

// ---------------------------------------------------------------------------
__global__ void k_prep(const int* __restrict__ mat,
                       uint32_t* __restrict__ seg1, uint32_t* __restrict__ seg2,
                       uint32_t* __restrict__ hdr1, uint32_t* __restrict__ hdr2) {
    int wid  = (blockIdx.x * blockDim.x + threadIdx.x) >> 6;
    int lane = threadIdx.x & 63;
    if (wid >= NSEG1 + NSEG2) return;

    int row0, col0;
    uint32_t *seg, *hdr;
    if (wid < NSEG1) {
        int rb = wid / S1_CH, ch = wid % S1_CH;
        row0 = rb * RB;          col0 = ch * C;
        seg = seg1 + (size_t)wid * SEG_U32;  hdr = hdr1 + wid;
    } else {
        int s  = wid - NSEG1;
        int rb = s / S2_CH, ch = s % S2_CH;
        row0 = N_HID + rb * RB;  col0 = ch * C;
        seg = seg2 + (size_t)s * SEG_U32;    hdr = hdr2 + s;
    }

    int n = 0;
    if (lane < RB) {
        // int4-vectorized row read: 8 x 16B loads (4x fewer transactions
        // than 32 scalar loads on this latency-bound uncoalesced pattern)
        const int4* m4 = (const int4*)(mat + (size_t)(row0 + lane) * SRC_DIM + col0);
        uint8_t* sb = (uint8_t*)seg;
        #pragma unroll
        for (int cc = 0; cc < 8; cc++) {
            int4 q4 = m4[cc];
            int codes[4] = {q4.x, q4.y, q4.z, q4.w};
            #pragma unroll
            for (int k = 0; k < 4; k++) {
                int code = codes[k];
                if (code != 0) {
                    int c = cc * 4 + k;
                    uint8_t slot = (uint8_t)((code - 1) * C + c);
                    if (n < 2) {
                        sb[2 * lane + n] = slot;           // plane-0 u16
                    } else {
                        int j  = n - 2;                    // overflow index
                        int pl = j >> 1;                   // 0-based ov plane
                        sb[(size_t)(8 + 9 * pl + 1 + (lane >> 1)) * 4
                           + (lane & 1) * 2 + (j & 1)] = slot;
                    }
                    n++;
                }
            }
        }
    }
    int m = n;
    #pragma unroll
    for (int d = 1; d < 64; d <<= 1) m = max(m, __shfl_xor(m, d));
    uint32_t Wv = (m <= 2) ? 1u : 1u + (uint32_t)((m - 1) >> 1);

    for (uint32_t p = 1; p < Wv; p++) {
        unsigned long long b = __ballot(n > (int)(2 * p));
        if (lane == 0) seg[8 + 9 * (p - 1)] = (uint32_t)(b & 0xFFFFu);
    }
    if (lane == 0) *hdr = Wv;
}

// ---------------------------------------------------------------------------
// k_xt: transpose x[8192][1024] -> x_t[1024][8192] (fp32), 64x64 LDS tiles.
// ---------------------------------------------------------------------------
__global__ __launch_bounds__(256) void k_xt(const float* __restrict__ x,
                                            float* __restrict__ x_t) {
    __shared__ float t[64][65];
    const int b0 = blockIdx.x * 64, c0 = blockIdx.y * 64;
    {
        int r  = threadIdx.x >> 4;
        int cq = (threadIdx.x & 15) * 4;
        #pragma unroll
        for (int k = 0; k < 4; k++) {
            int rr = r + 16 * k;
            float4 v = *(const float4*)&x[(size_t)(b0 + rr) * IN_DIM + c0 + cq];
            t[rr][cq + 0] = v.x; t[rr][cq + 1] = v.y;
            t[rr][cq + 2] = v.z; t[rr][cq + 3] = v.w;
        }
    }
    __syncthreads();
    {
        int bq  = (threadIdx.x & 15) * 4;
        int cc0 = threadIdx.x >> 4;
        #pragma unroll
        for (int k = 0; k < 4; k++) {
            int cc = cc0 + 16 * k;
            float4 v;
            v.x = t[bq + 0][cc]; v.y = t[bq + 1][cc];
            v.z = t[bq + 2][cc]; v.w = t[bq + 3][cc];
            *(float4*)&x_t[(size_t)(c0 + cc) * BATCH + b0 + bq] = v;
        }
    }
}

typedef float v2f __attribute__((ext_vector_type(2)));

// pack two floats as bf16 pair: low16 = first, high16 = second
__device__ __forceinline__ uint32_t pack2(float a, float b) {
    __hip_bfloat162 h = __float22bfloat162_rn(make_float2(a, b));
    union { __hip_bfloat162 h2; uint32_t u; } u;
    u.h2 = h;
    return u.u;
}

__device__ __forceinline__ float rcp_f(float x) { return __builtin_amdgcn_rcpf(x); }

// write 4 activation slots for column c, 4 batches per lane (v pre-scaled by w).
// Trans budget/elem: 1 v_exp + 2 v_rcp.
__device__ __forceinline__ void write_acts4(uint32_t* As, int c, int lane, float4 v) {
    *(uint2*)&As[(size_t)(0 * C + c) * 128 + 2 * lane] =
        make_uint2(pack2(v.x, v.y), pack2(v.z, v.w));
    *(uint2*)&As[(size_t)(1 * C + c) * 128 + 2 * lane] =
        make_uint2(pack2(fmaxf(v.x, 0.0f), fmaxf(v.y, 0.0f)),
                   pack2(fmaxf(v.z, 0.0f), fmaxf(v.w, 0.0f)));
    float ex = __expf(-v.x), ey = __expf(-v.y);
    float ez = __expf(-v.z), ew = __expf(-v.w);
    float tx = fmaf(2.0f, rcp_f(fmaf(ex, ex, 1.0f)), -1.0f);
    float ty = fmaf(2.0f, rcp_f(fmaf(ey, ey, 1.0f)), -1.0f);
    float tz = fmaf(2.0f, rcp_f(fmaf(ez, ez, 1.0f)), -1.0f);
    float tw = fmaf(2.0f, rcp_f(fmaf(ew, ew, 1.0f)), -1.0f);
    *(uint2*)&As[(size_t)(2 * C + c) * 128 + 2 * lane] =
        make_uint2(pack2(tx, ty), pack2(tz, tw));
    float sx = rcp_f(1.0f + ex), sy = rcp_f(1.0f + ey);
    float sz = rcp_f(1.0f + ez), sw = rcp_f(1.0f + ew);
    *(uint2*)&As[(size_t)(3 * C + c) * 128 + 2 * lane] =
        make_uint2(pack2(sx, sy), pack2(sz, sw));
}

// one slot: ds_read_b64 -> 2 bf16-pairs -> 2 v_pk_add_f32 (4 batches/lane)
#define SLOT_ACC(AB, R, S)                                                     \
    {                                                                          \
        uint2 q_ = *(const uint2*)&(AB)[(size_t)(S) * 128 + 2 * lane];         \
        v2f ua_, ub_;                                                          \
        ua_.x = __uint_as_float(q_.x << 16);                                   \
        ua_.y = __uint_as_float(q_.x & 0xFFFF0000u);                           \
        ub_.x = __uint_as_float(q_.y << 16);                                   \
        ub_.y = __uint_as_float(q_.y & 0xFFFF0000u);                           \
        accA[R] += ua_;                                                        \
        accB[R] += ub_;                                                        \
    }

// v5: plane-0 unconditional (pads hit zero page); overflow planes granule-2,
// scalar-gated, words loaded INSIDE the guard (R4 lesson).
#define EDGE_PLANES(AB, SEGBASE, WVAL)                                         \
    {                                                                          \
        const uint32_t* sp_ = (SEGBASE);                                       \
        _Pragma("unroll")                                                      \
        for (int i = 0; i < 8; i++) {                                          \
            uint32_t g = RFL(sp_[i]);                                          \
            SLOT_ACC(AB, 2 * i,     g & 255u)                                  \
            SLOT_ACC(AB, 2 * i,     (g >> 8) & 255u)                           \
            SLOT_ACC(AB, 2 * i + 1, (g >> 16) & 255u)                          \
            SLOT_ACC(AB, 2 * i + 1, g >> 24)                                   \
        }                                                                      \
        _Pragma("unroll 1")                                                    \
        for (uint32_t p = 1; p < (WVAL); p++) {                                \
            const uint32_t* pp_ = sp_ + 8 + 9 * (p - 1);                       \
            uint32_t mask = RFL(pp_[0]);                                       \
            _Pragma("unroll")                                                  \
            for (int r = 0; r < RB; r++) {                                     \
                if (mask & (1u << r)) {                                        \
                    uint32_t h_ = RFL(pp_[1 + (r >> 1)]);                      \
                    uint32_t u_ = (r & 1) ? (h_ >> 16) : h_;                   \
                    SLOT_ACC(AB, r, u_ & 255u)                                 \
                    SLOT_ACC(AB, r, (u_ >> 8) & 255u)                          \
                }                                                              \
            }                                                                  \
        }                                                                      \
    }

// ---------------------------------------------------------------------------
// Stage 1: 16 waves x 16 rows = 256 rows; 256 batches; 16 chunks (chunk-group).
// Grid (32 tiles, 8 row splits, 2 chunk groups) = 512 blocks = 2/CU.
// SINGLE-buffered A-tile (66 KB x 2 blocks = 132 KB/CU); 2 barriers/chunk --
// cheap when a co-resident block fills the gaps (R0 regime). Output: bf16
// partial hidden plane per chunk-group (summed in k_out loads).
// ---------------------------------------------------------------------------
__global__ __launch_bounds__(1024, 4) void k_hid(const float* __restrict__ x_t,
                                                 const float* __restrict__ wp,
                                                 const uint32_t* __restrict__ seg1,
                                                 const uint32_t* __restrict__ hdr1,
                                                 __hip_bfloat16* __restrict__ hidden_t) {
    __shared__ uint32_t As[ABUF_U32];           // 64.5 KB single buffer

    const float w  = wp[0];
    const int tile = blockIdx.x;                // 0..31
    const int cg   = blockIdx.z;                // 0..1 (chunk group)
    const int lane = threadIdx.x & 63;
    const int wv   = __builtin_amdgcn_readfirstlane(threadIdx.x >> 6); // 0..15
    const int rb   = blockIdx.y * 16 + wv;      // row-block 0..127
    const int b0   = tile * BT;
    const int c0   = cg * (S1_CH / 2);          // first chunk of this group

    if (threadIdx.x < 128) As[ZSLOT * 128 + threadIdx.x] = 0u;

    v2f accA[RB], accB[RB];
    #pragma unroll
    for (int r = 0; r < RB; r++) {
        accA[r] = (v2f)0.0f;
        accB[r] = (v2f)0.0f;
    }

    // prefetch chunk c0: each wave owns 2 columns, 4 batches/lane
    float4 v[2];
    #pragma unroll
    for (int j = 0; j < 2; j++) {
        int gcol = c0 * C + wv * 2 + j;
        const float2* xp = (const float2*)&x_t[(size_t)gcol * BATCH + b0];
        float2 u0 = xp[lane], u1 = xp[64 + lane];
        v[j] = make_float4(w * u0.x, w * u0.y, w * u1.x, w * u1.y);
    }

    #pragma unroll 1
    for (int cj = 0; cj < S1_CH / 2; cj++) {
        int ch = c0 + cj;
        __syncthreads();                        // edge-phase(ch-1) done (WAR)
        write_acts4(As, wv * 2 + 0, lane, v[0]);
        write_acts4(As, wv * 2 + 1, lane, v[1]);
        __syncthreads();                        // acts visible
        if (cj + 1 < S1_CH / 2) {               // prefetch next chunk
            #pragma unroll
            for (int j = 0; j < 2; j++) {
                int gcol = (ch + 1) * C + wv * 2 + j;
                const float2* xp = (const float2*)&x_t[(size_t)gcol * BATCH + b0];
                float2 u0 = xp[lane], u1 = xp[64 + lane];
                v[j] = make_float4(w * u0.x, w * u0.y, w * u1.x, w * u1.y);
            }
        }
        int sidx = rb * S1_CH + ch;
        uint32_t W = RFL(hdr1[sidx]);
        EDGE_PLANES(As, seg1 + (size_t)sidx * SEG_U32, W)
    }

    __hip_bfloat16* hout = hidden_t + (size_t)cg * N_HID * BATCH;
    const int row0 = rb * RB;
    #pragma unroll
    for (int r = 0; r < RB; r++) {
        *(uint32_t*)&hout[(size_t)(row0 + r) * BATCH + b0 + 2 * lane] =
            pack2(accA[r].x, accA[r].y);
        *(uint32_t*)&hout[(size_t)(row0 + r) * BATCH + b0 + 128 + 2 * lane] =
            pack2(accB[r].x, accB[r].y);
    }
}

// source loader for stage 2: x_t fp32, or SUM of 2 bf16 partial hidden planes
__device__ __forceinline__ float4 load_src4(const float* __restrict__ x_t,
                                            const __hip_bfloat16* __restrict__ hidden_t,
                                            int gcol, int b0, int lane, float w) {
    if (gcol < IN_DIM) {
        const float2* xp = (const float2*)&x_t[(size_t)gcol * BATCH + b0];
        float2 u0 = xp[lane], u1 = xp[64 + lane];
        return make_float4(w * u0.x, w * u0.y, w * u1.x, w * u1.y);
    } else {
        const uint16_t* hp = (const uint16_t*)&hidden_t[(size_t)(gcol - IN_DIM) * BATCH + b0];
        const uint16_t* hq = hp + (size_t)N_HID * BATCH;   // partial plane 1
        uint32_t a0 = *(const uint32_t*)&hp[2 * lane];
        uint32_t a1 = *(const uint32_t*)&hp[128 + 2 * lane];
        uint32_t b0w = *(const uint32_t*)&hq[2 * lane];
        uint32_t b1w = *(const uint32_t*)&hq[128 + 2 * lane];
        float hx = __uint_as_float(a0 << 16)         + __uint_as_float(b0w << 16);
        float hy = __uint_as_float(a0 & 0xFFFF0000u) + __uint_as_float(b0w & 0xFFFF0000u);
        float hz = __uint_as_float(a1 << 16)         + __uint_as_float(b1w << 16);
        float hw2 = __uint_as_float(a1 & 0xFFFF0000u) + __uint_as_float(b1w & 0xFFFF0000u);
        return make_float4(w * hx, w * hy, w * hz, w * hw2);
    }
}

// ---------------------------------------------------------------------------
// Stage 2: 16 waves x 16 rows = ALL 256 out rows; 256 batches per block.
// Grid (32 tiles, 8 chunk groups of 12) = 256 blocks. Dbuf (proven R3 form).
// ---------------------------------------------------------------------------
__global__ __launch_bounds__(1024, 4) void k_out(const float* __restrict__ x_t,
                                                 const __hip_bfloat16* __restrict__ hidden_t,
                                                 const float* __restrict__ wp,
                                                 const uint32_t* __restrict__ seg2,
                                                 const uint32_t* __restrict__ hdr2,
                                                 uint32_t* __restrict__ partials) {
    __shared__ uint32_t As[2 * ABUF_U32];

    const float w  = wp[0];
    const int tile = blockIdx.x;                // 0..31
    const int cg   = blockIdx.y;                // 0..7
    const int lane = threadIdx.x & 63;
    const int wv   = __builtin_amdgcn_readfirstlane(threadIdx.x >> 6); // 0..15
    const int b0   = tile * BT;

    if (threadIdx.x < 128) {
        As[ZSLOT * 128 + threadIdx.x] = 0u;
        As[ABUF_U32 + ZSLOT * 128 + threadIdx.x] = 0u;
    }

    v2f accA[RB], accB[RB];
    #pragma unroll
    for (int r = 0; r < RB; r++) {
        accA[r] = (v2f)0.0f;
        accB[r] = (v2f)0.0f;
    }

    float4 v[2];
    #pragma unroll
    for (int j = 0; j < 2; j++)
        v[j] = load_src4(x_t, hidden_t, (cg * 12) * C + wv * 2 + j, b0, lane, w);
    write_acts4(As, wv * 2 + 0, lane, v[0]);
    write_acts4(As, wv * 2 + 1, lane, v[1]);
    #pragma unroll
    for (int j = 0; j < 2; j++)
        v[j] = load_src4(x_t, hidden_t, (cg * 12 + 1) * C + wv * 2 + j, b0, lane, w);
    __syncthreads();

    #pragma unroll 1
    for (int cj = 0; cj < 12; cj++) {
        int ch = cg * 12 + cj;
        uint32_t* cur = As + (size_t)(cj & 1) * ABUF_U32;
        uint32_t* nxt = As + (size_t)((cj + 1) & 1) * ABUF_U32;
        if (cj + 1 < 12) {
            write_acts4(nxt, wv * 2 + 0, lane, v[0]);
            write_acts4(nxt, wv * 2 + 1, lane, v[1]);
            if (cj + 2 < 12) {
                #pragma unroll
                for (int j = 0; j < 2; j++)
                    v[j] = load_src4(x_t, hidden_t, (ch + 2) * C + wv * 2 + j, b0, lane, w);
            }
        }
        int sidx = wv * S2_CH + ch;              // wv = row-block 0..15
        uint32_t W = RFL(hdr2[sidx]);
        EDGE_PLANES(cur, seg2 + (size_t)sidx * SEG_U32, W)
        __syncthreads();
    }

    #pragma unroll
    for (int r = 0; r < RB; r++) {
        size_t base = ((size_t)cg * OUT_DIM + wv * RB + r) * (BATCH / 2) + (b0 >> 1);
        partials[base + lane]      = pack2(accA[r].x, accA[r].y);
        partials[base + 64 + lane] = pack2(accB[r].x, accB[r].y);
    }
}

// ---------------------------------------------------------------------------
// k_sum: reduce 8 bf16-packed partial planes + transpose -> out[b][r].
// Block: 128 batches x 16 rows. Grid (64, 16).
// ---------------------------------------------------------------------------
__global__ __launch_bounds__(256) void k_sum(const uint32_t* __restrict__ partials,
                                             float* __restrict__ out) {
    __shared__ float t[16][130];
    const int b0 = blockIdx.x * 128, r0 = blockIdx.y * 16;
    const int lane = threadIdx.x & 63;
    const int g4   = threadIdx.x >> 6;          // 0..3

    #pragma unroll
    for (int k = 0; k < 4; k++) {
        int rr = g4 * 4 + k;
        float sx = 0.0f, sy = 0.0f;
        #pragma unroll
        for (int cg = 0; cg < 8; cg++) {
            uint32_t q = partials[((size_t)cg * OUT_DIM + r0 + rr) * (BATCH / 2)
                                  + (b0 >> 1) + lane];
            sx += __uint_as_float(q << 16);
            sy += __uint_as_float(q & 0xFFFF0000u);
        }
        t[rr][2 * lane]     = sx;
        t[rr][2 * lane + 1] = sy;
    }
    __syncthreads();
    #pragma unroll
    for (int k = 0; k < 2; k++) {
        int idx = threadIdx.x + 256 * k;        // 0..511
        int bb = idx >> 2, rq = idx & 3;
        float4 v;
        v.x = t[rq * 4 + 0][bb];
        v.y = t[rq * 4 + 1][bb];
        v.z = t[rq * 4 + 2][bb];
        v.w = t[rq * 4 + 3][bb];
        *(float4*)&out[(size_t)(b0 + bb) * OUT_DIM + r0 + rq * 4] = v;
    }
}

// ---------------------------------------------------------------------------
extern "C" void kernel_launch(void* const* d_in, const int* in_sizes, int n_in,
                              void* d_out, int out_size, void* d_ws, size_t ws_size,
                              hipStream_t stream) {
    const float* x   = (const float*)d_in[0];
    const float* w   = (const float*)d_in[1];
    const int*   mat = (const int*)d_in[2];
    float* out = (float*)d_out;

    uint8_t* ws = (uint8_t*)d_ws;
    size_t off = 0;
    __hip_bfloat16* hidden_t = (__hip_bfloat16*)(ws + off);
    off += (size_t)2 * BATCH * N_HID * 2;                                      // 67.1 MB (2 planes)
    float* x_t = (float*)(ws + off);        off += (size_t)IN_DIM * BATCH * 4; // 33.6 MB
    uint32_t* seg1 = (uint32_t*)(ws + off); off += (size_t)NSEG1 * SEG_U32 * 4;//  2.62 MB
    uint32_t* seg2 = (uint32_t*)(ws + off); off += (size_t)NSEG2 * SEG_U32 * 4;//  0.98 MB
    uint32_t* hdr1 = (uint32_t*)(ws + off); off += (size_t)NSEG1 * 4;
    uint32_t* hdr2 = (uint32_t*)(ws + off); off += (size_t)NSEG2 * 4;
    uint32_t* partials = (uint32_t*)(ws + off);
    off += (size_t)8 * OUT_DIM * (BATCH / 2) * 4;                              // 33.6 MB
    (void)ws_size; (void)in_sizes; (void)n_in; (void)out_size;

    hipMemsetAsync(seg1, 0x80, (size_t)(NSEG1 + NSEG2) * SEG_U32 * 4, stream);

    {
        int nseg = NSEG1 + NSEG2;                   // 5632 waves
        k_prep<<<(nseg + 3) / 4, 256, 0, stream>>>(mat, seg1, seg2, hdr1, hdr2);
    }
    {
        dim3 g(BATCH / 64, IN_DIM / 64);            // 128 x 16
        k_xt<<<g, 256, 0, stream>>>(x, x_t);
    }
    {
        dim3 g(BATCH / BT, 8, 2);                   // 32 x 8 x 2 = 512 blocks
        k_hid<<<g, 1024, 0, stream>>>(x_t, w, seg1, hdr1, hidden_t);
    }
    {
        dim3 g(BATCH / BT, 8);                      // 32 x 8 = 256 blocks
        k_out<<<g, 1024, 0, stream>>>(x_t, hidden_t, w, seg2, hdr2, partials);
    }
    {
        dim3 g(BATCH / 128, OUT_DIM / 16);          // 64 x 16 = 1024 blocks
        k_sum<<<g, 256, 0, stream>>>(partials, out);
    }
}